// Round 2
// baseline (1989.197 us; speedup 1.0000x reference)
//
#include <hip/hip_runtime.h>
#include <hip/hip_bf16.h>
#include <math.h>

// ---------------- problem dims (fixed by setup_inputs) ----------------
constexpr int B  = 8,  V = 64, E = 512, NS = 32;
constexpr int L  = 4,  H = 8,  D = 64,  M  = 1024, R = 128;
constexpr int HD = H * D;            // 512
constexpr int ROWS  = B * V;         // 512 distinct transformer rows
constexpr int SROWS = ROWS * NS;     // 16384 sample rows

// ---------------- threefry2x32-20 (JAX-compatible) ----------------
struct TF2 { unsigned a, b; };
__host__ __device__ constexpr unsigned rotl32(unsigned x, int d) {
  return (x << d) | (x >> (32 - d));
}
__host__ __device__ constexpr TF2 threefry(unsigned k0, unsigned k1,
                                           unsigned x0, unsigned x1) {
  unsigned ks2 = k0 ^ k1 ^ 0x1BD11BDAu;
  x0 += k0; x1 += k1;
  const int ra[4] = {13, 15, 26, 6};
  const int rb[4] = {17, 29, 16, 24};
  for (int i = 0; i < 4; i++) { x0 += x1; x1 = rotl32(x1, ra[i]); x1 ^= x0; }
  x0 += k1;  x1 += ks2 + 1u;
  for (int i = 0; i < 4; i++) { x0 += x1; x1 = rotl32(x1, rb[i]); x1 ^= x0; }
  x0 += ks2; x1 += k0 + 2u;
  for (int i = 0; i < 4; i++) { x0 += x1; x1 = rotl32(x1, ra[i]); x1 ^= x0; }
  x0 += k0;  x1 += k1 + 3u;
  for (int i = 0; i < 4; i++) { x0 += x1; x1 = rotl32(x1, rb[i]); x1 ^= x0; }
  x0 += k1;  x1 += ks2 + 4u;
  for (int i = 0; i < 4; i++) { x0 += x1; x1 = rotl32(x1, ra[i]); x1 ^= x0; }
  x0 += ks2; x1 += k0 + 5u;
  return {x0, x1};
}

// JAX threefry_partitionable=True (default since jax 0.4.30) 32-bit bits:
// per-element j (64-bit iota; hi=0 for our sizes): bits = out0 ^ out1
__device__ __forceinline__ unsigned tf_bits32(unsigned k0, unsigned k1,
                                              unsigned j) {
  TF2 r = threefry(k0, k1, 0u, j);
  return r.a ^ r.b;
}

// ---------------- block/wave reductions ----------------
__device__ __forceinline__ double waveReduceAdd64(double v) {
#pragma unroll
  for (int m = 32; m; m >>= 1) v += __shfl_xor(v, m, 64);
  return v;
}

// ---------------- keys/vals projection: 64 GEMMs [512 x 64 x K=512] ----------------
// grid: (16, 64)  blockIdx.x = 32-row tile, blockIdx.y = is_v*32 + l*8 + h
__global__ __launch_bounds__(256) void kv_gemm(
    const float* __restrict__ flow, const float* __restrict__ Wk,
    const float* __restrict__ bk, const float* __restrict__ Wv,
    const float* __restrict__ bv, float* __restrict__ keys,
    float* __restrict__ vals) {
  __shared__ float As[32][65];
  __shared__ float Bs[64][64];
  const int t = threadIdx.x;
  const int sel = blockIdx.y;
  const int is_v = sel >> 5;
  const int lh = sel & 31;            // l*8 + h
  const int l = lh >> 3, h = lh & 7;
  const float* W  = (is_v ? Wv : Wk) + lh * (E * D);
  const float* bb = (is_v ? bv : bk) + lh * D;
  float* outp = is_v ? vals : keys;
  const int m0 = blockIdx.x * 32;
  const int tx = t & 15, ty = t >> 4;
  double acc[2][4] = {};
  for (int k0 = 0; k0 < E; k0 += 64) {
#pragma unroll
    for (int i = 0; i < 8; i++) {
      int idx = i * 256 + t, r = idx >> 6, c = idx & 63;
      As[r][c] = flow[(m0 + r) * E + k0 + c];
    }
#pragma unroll
    for (int i = 0; i < 16; i++) {
      int idx = i * 256 + t, r = idx >> 6, c = idx & 63;
      Bs[r][c] = W[(k0 + r) * D + c];
    }
    __syncthreads();
#pragma unroll 4
    for (int kk = 0; kk < 64; kk++) {
      double a0 = (double)As[ty * 2 + 0][kk];
      double a1 = (double)As[ty * 2 + 1][kk];
      double b0 = (double)Bs[kk][tx * 4 + 0];
      double b1 = (double)Bs[kk][tx * 4 + 1];
      double b2 = (double)Bs[kk][tx * 4 + 2];
      double b3 = (double)Bs[kk][tx * 4 + 3];
      acc[0][0] += a0 * b0; acc[0][1] += a0 * b1;
      acc[0][2] += a0 * b2; acc[0][3] += a0 * b3;
      acc[1][0] += a1 * b0; acc[1][1] += a1 * b1;
      acc[1][2] += a1 * b2; acc[1][3] += a1 * b3;
    }
    __syncthreads();
  }
#pragma unroll
  for (int i = 0; i < 2; i++)
#pragma unroll
    for (int j = 0; j < 4; j++) {
      int m = m0 + ty * 2 + i;        // row = b*64 + v
      int d = tx * 4 + j;
      int b_ = m >> 6, v_ = m & 63;
      float out = (float)(acc[i][j] + (double)bb[d]);
      outp[(((l * B + b_) * H + h) * V + v_) * D + d] = out;
    }
}

// ---------------- generic GEMM: C[M,N] = A[M,K] @ W[K,N] + bias, opt ReLU ----------------
// grid: (N/64, M/32), 256 threads, fp64 accumulation
template <bool RELU>
__global__ __launch_bounds__(256) void gemm_bias(
    const float* __restrict__ A, const float* __restrict__ W,
    const float* __restrict__ bias, float* __restrict__ C,
    int Mdim, int Ndim, int Kdim) {
  __shared__ float As[32][65];
  __shared__ float Bs[64][64];
  const int t = threadIdx.x;
  const int n0 = blockIdx.x * 64;
  const int m0 = blockIdx.y * 32;
  const int tx = t & 15, ty = t >> 4;
  double acc[2][4] = {};
  for (int k0 = 0; k0 < Kdim; k0 += 64) {
#pragma unroll
    for (int i = 0; i < 8; i++) {
      int idx = i * 256 + t, r = idx >> 6, c = idx & 63;
      As[r][c] = A[(m0 + r) * Kdim + k0 + c];
    }
#pragma unroll
    for (int i = 0; i < 16; i++) {
      int idx = i * 256 + t, r = idx >> 6, c = idx & 63;
      Bs[r][c] = W[(k0 + r) * Ndim + n0 + c];
    }
    __syncthreads();
#pragma unroll 4
    for (int kk = 0; kk < 64; kk++) {
      double a0 = (double)As[ty * 2 + 0][kk];
      double a1 = (double)As[ty * 2 + 1][kk];
      double b0 = (double)Bs[kk][tx * 4 + 0];
      double b1 = (double)Bs[kk][tx * 4 + 1];
      double b2 = (double)Bs[kk][tx * 4 + 2];
      double b3 = (double)Bs[kk][tx * 4 + 3];
      acc[0][0] += a0 * b0; acc[0][1] += a0 * b1;
      acc[0][2] += a0 * b2; acc[0][3] += a0 * b3;
      acc[1][0] += a1 * b0; acc[1][1] += a1 * b1;
      acc[1][2] += a1 * b2; acc[1][3] += a1 * b3;
    }
    __syncthreads();
  }
#pragma unroll
  for (int i = 0; i < 2; i++)
#pragma unroll
    for (int j = 0; j < 4; j++) {
      int m = m0 + ty * 2 + i, n = n0 + tx * 4 + j;
      float out = (float)(acc[i][j] + (double)bias[n]);
      if (RELU) out = fmaxf(out, 0.0f);
      C[m * Ndim + n] = out;
    }
}

// ---------------- fused attention + residual + LN1 (one block per row) ----------------
__global__ __launch_bounds__(256) void attn_kernel(
    float* __restrict__ att, const float* __restrict__ keys,
    const float* __restrict__ vals, const float* __restrict__ g,
    const float* __restrict__ bb, int l) {
  __shared__ float q[HD];
  __shared__ float sp[HD];             // scores -> probs (in place)
  __shared__ double rb[8];
  const int t = threadIdx.x;
  const int row = blockIdx.x;          // b*64 + v
  const int b_ = row >> 6;
  q[t]       = att[row * HD + t];
  q[t + 256] = att[row * HD + 256 + t];
  __syncthreads();
  // scores[h][w] = 0.125 * sum_d q[h*64+d] * K[l,b,h,w,d]
#pragma unroll
  for (int rep = 0; rep < 2; rep++) {
    int idx = t + rep * 256;
    int h = idx >> 6, w = idx & 63;
    const float* kp = keys + (((l * B + b_) * H + h) * V + w) * D;
    const float* qp = q + h * D;
    double s = 0.0;
#pragma unroll 8
    for (int d = 0; d < 64; d++) s += (double)qp[d] * (double)kp[d];
    sp[idx] = (float)s * 0.125f;       // round like ref (f32 einsum, exact *2^-3)
  }
  __syncthreads();
  // softmax over w per head: thread -> (h = t>>5, w0 = t&31, w1 = w0+32)
  {
    int h = t >> 5, w0 = t & 31;
    float s0 = sp[h * 64 + w0], s1 = sp[h * 64 + w0 + 32];
    float mx = fmaxf(s0, s1);
#pragma unroll
    for (int m = 16; m; m >>= 1) mx = fmaxf(mx, __shfl_xor(mx, m, 32));
    float e0 = expf(s0 - mx), e1 = expf(s1 - mx);
    double sm = (double)e0 + (double)e1;
#pragma unroll
    for (int m = 16; m; m >>= 1) sm += __shfl_xor(sm, m, 32);
    sp[h * 64 + w0]      = (float)((double)e0 / sm);
    sp[h * 64 + w0 + 32] = (float)((double)e1 / sm);
  }
  __syncthreads();
  // a[h][d] = sum_w p[h][w] * Vv[l,b,h,w,d]; x = att + a ; then LN
  float x[2];
#pragma unroll
  for (int rep = 0; rep < 2; rep++) {
    int idx = t + rep * 256;
    int h = idx >> 6, d = idx & 63;
    const float* vp = vals + (((l * B + b_) * H + h) * V) * D + d;
    const float* pp = sp + h * 64;
    double a = 0.0;
#pragma unroll 8
    for (int w = 0; w < 64; w++) a += (double)pp[w] * (double)vp[w * 64];
    x[rep] = q[idx] + (float)a;        // f32 residual add, matches ref
  }
  double s1 = (double)x[0] + (double)x[1];
  double s2 = (double)x[0] * (double)x[0] + (double)x[1] * (double)x[1];
  s1 = waveReduceAdd64(s1);
  s2 = waveReduceAdd64(s2);
  const int wid = t >> 6, lane = t & 63;
  if (lane == 0) { rb[wid] = s1; rb[4 + wid] = s2; }
  __syncthreads();
  double S1 = rb[0] + rb[1] + rb[2] + rb[3];
  double S2 = rb[4] + rb[5] + rb[6] + rb[7];
  double mean = S1 / (double)HD;
  double var  = S2 / (double)HD - mean * mean;
  double inv  = 1.0 / sqrt(var + (double)1e-5f);
  att[row * HD + t] =
      (float)(((double)x[0] - mean) * inv * (double)g[t] + (double)bb[t]);
  att[row * HD + 256 + t] =
      (float)(((double)x[1] - mean) * inv * (double)g[t + 256] + (double)bb[t + 256]);
}

// ---------------- residual + LN2 (one block per row) ----------------
__global__ __launch_bounds__(256) void ln_res_kernel(
    float* __restrict__ att, const float* __restrict__ h3,
    const float* __restrict__ g, const float* __restrict__ bb) {
  __shared__ double rb[8];
  const int t = threadIdx.x;
  const int row = blockIdx.x;
  float x0 = att[row * HD + t] + h3[row * HD + t];
  float x1 = att[row * HD + 256 + t] + h3[row * HD + 256 + t];
  double s1 = (double)x0 + (double)x1;
  double s2 = (double)x0 * (double)x0 + (double)x1 * (double)x1;
  s1 = waveReduceAdd64(s1);
  s2 = waveReduceAdd64(s2);
  const int wid = t >> 6, lane = t & 63;
  if (lane == 0) { rb[wid] = s1; rb[4 + wid] = s2; }
  __syncthreads();
  double S1 = rb[0] + rb[1] + rb[2] + rb[3];
  double S2 = rb[4] + rb[5] + rb[6] + rb[7];
  double mean = S1 / (double)HD;
  double var  = S2 / (double)HD - mean * mean;
  double inv  = 1.0 / sqrt(var + (double)1e-5f);
  att[row * HD + t] =
      (float)(((double)x0 - mean) * inv * (double)g[t] + (double)bb[t]);
  att[row * HD + 256 + t] =
      (float)(((double)x1 - mean) * inv * (double)g[t + 256] + (double)bb[t + 256]);
}

// ---------------- gumbel-argmax sampling (one wave per sample row) ----------------
__global__ __launch_bounds__(256) void sample_kernel(
    const float* __restrict__ logits, float* __restrict__ out) {
  constexpr TF2 KC = threefry(0u, 1u, 0u, 0u);  // fold_in(key(1), 0)
  constexpr TF2 KU = threefry(0u, 1u, 0u, 1u);  // fold_in(key(1), 1)
  const int lane = threadIdx.x & 63;
  const int wid = threadIdx.x >> 6;
  const int row = blockIdx.x * 4 + wid;            // [0, 16384)
  const float* lrow = logits + (row >> 5) * R;     // logits shared across n
  float bv = -1e30f;
  int bi = 0;
#pragma unroll
  for (int rep = 0; rep < 2; rep++) {
    int r = lane + rep * 64;
    unsigned j = (unsigned)row * (unsigned)R + (unsigned)r;
    unsigned bits = tf_bits32(KC.a, KC.b, j);      // partitionable threefry
    float f = __uint_as_float((bits >> 9) | 0x3f800000u) - 1.0f;
    float u = fmaxf(f, 1.17549435e-38f);           // uniform(minval=tiny)
    float gv = -logf(-logf(u));                    // fp32, matches JAX gumbel
    float v = lrow[r] + gv;
    if (v > bv) { bv = v; bi = r; }                // strict >: first-max kept
  }
#pragma unroll
  for (int m = 32; m; m >>= 1) {
    float ov = __shfl_xor(bv, m, 64);
    int oi = __shfl_xor(bi, m, 64);
    if (ov > bv || (ov == bv && oi < bi)) { bv = ov; bi = oi; }
  }
  if (lane == 0) {
    unsigned ub = tf_bits32(KU.a, KU.b, (unsigned)row);
    float u = __uint_as_float((ub >> 9) | 0x3f800000u) - 1.0f;
    out[row] = ((float)bi + u) * (1.0f / 128.0f);  // /128 exact pow2
  }
}

// ---------------- launcher ----------------
extern "C" void kernel_launch(void* const* d_in, const int* in_sizes, int n_in,
                              void* d_out, int out_size, void* d_ws,
                              size_t ws_size, hipStream_t stream) {
  (void)in_sizes; (void)n_in; (void)out_size; (void)ws_size;
  const float* flow = (const float*)d_in[0];
  const float* Wsh  = (const float*)d_in[1];
  const float* bsh  = (const float*)d_in[2];
  const float* Wk   = (const float*)d_in[3];
  const float* bk   = (const float*)d_in[4];
  const float* Wv   = (const float*)d_in[5];
  const float* bv   = (const float*)d_in[6];
  const float* ln1g = (const float*)d_in[7];
  const float* ln1b = (const float*)d_in[8];
  const float* W1   = (const float*)d_in[9];
  const float* b1   = (const float*)d_in[10];
  const float* W2   = (const float*)d_in[11];
  const float* b2   = (const float*)d_in[12];
  const float* W3   = (const float*)d_in[13];
  const float* b3   = (const float*)d_in[14];
  const float* ln2g = (const float*)d_in[15];
  const float* ln2b = (const float*)d_in[16];
  const float* Wd   = (const float*)d_in[17];
  const float* bd   = (const float*)d_in[18];

  float* ws = (float*)d_ws;
  float* keys   = ws;                        // L*B*H*V*D = 1,048,576
  float* vals   = keys + L * B * H * V * D;  // 1,048,576
  float* att    = vals + L * B * H * V * D;  // 512*512
  float* h1     = att + ROWS * HD;           // 512*1024
  float* h2     = h1 + ROWS * M;             // 512*1024
  float* h3     = h2 + ROWS * M;             // 512*512
  float* logits = h3 + ROWS * HD;            // 512*128  (~15 MB total ws)

  kv_gemm<<<dim3(ROWS / 32, 2 * L * H), 256, 0, stream>>>(flow, Wk, bk, Wv, bv,
                                                          keys, vals);
  gemm_bias<false><<<dim3(HD / 64, ROWS / 32), 256, 0, stream>>>(
      flow, Wsh, bsh, att, ROWS, HD, E);
  for (int l = 0; l < L; l++) {
    attn_kernel<<<ROWS, 256, 0, stream>>>(att, keys, vals, ln1g + l * HD,
                                          ln1b + l * HD, l);
    gemm_bias<true><<<dim3(M / 64, ROWS / 32), 256, 0, stream>>>(
        att, W1 + l * HD * M, b1 + l * M, h1, ROWS, M, HD);
    gemm_bias<true><<<dim3(M / 64, ROWS / 32), 256, 0, stream>>>(
        h1, W2 + l * M * M, b2 + l * M, h2, ROWS, M, M);
    gemm_bias<false><<<dim3(HD / 64, ROWS / 32), 256, 0, stream>>>(
        h2, W3 + l * M * HD, b3 + l * HD, h3, ROWS, HD, M);
    ln_res_kernel<<<ROWS, 256, 0, stream>>>(att, h3, ln2g + l * HD,
                                            ln2b + l * HD);
  }
  gemm_bias<false><<<dim3(R / 64, ROWS / 32), 256, 0, stream>>>(
      att, Wd, bd, logits, ROWS, R, HD);
  sample_kernel<<<SROWS / 4, 256, 0, stream>>>(logits, (float*)d_out);
}

// Round 3
// 1195.123 us; speedup vs baseline: 1.6644x; 1.6644x over previous
//
#include <hip/hip_runtime.h>
#include <hip/hip_bf16.h>
#include <math.h>

// ---------------- problem dims (fixed by setup_inputs) ----------------
constexpr int B  = 8,  V = 64, E = 512, NS = 32;
constexpr int L  = 4,  H = 8,  D = 64,  M  = 1024, R = 128;
constexpr int HD = H * D;            // 512
constexpr int ROWS  = B * V;         // 512 distinct transformer rows
constexpr int SROWS = ROWS * NS;     // 16384 sample rows

// ---------------- threefry2x32-20 (JAX-compatible) ----------------
struct TF2 { unsigned a, b; };
__host__ __device__ constexpr unsigned rotl32(unsigned x, int d) {
  return (x << d) | (x >> (32 - d));
}
__host__ __device__ constexpr TF2 threefry(unsigned k0, unsigned k1,
                                           unsigned x0, unsigned x1) {
  unsigned ks2 = k0 ^ k1 ^ 0x1BD11BDAu;
  x0 += k0; x1 += k1;
  const int ra[4] = {13, 15, 26, 6};
  const int rb[4] = {17, 29, 16, 24};
  for (int i = 0; i < 4; i++) { x0 += x1; x1 = rotl32(x1, ra[i]); x1 ^= x0; }
  x0 += k1;  x1 += ks2 + 1u;
  for (int i = 0; i < 4; i++) { x0 += x1; x1 = rotl32(x1, rb[i]); x1 ^= x0; }
  x0 += ks2; x1 += k0 + 2u;
  for (int i = 0; i < 4; i++) { x0 += x1; x1 = rotl32(x1, ra[i]); x1 ^= x0; }
  x0 += k0;  x1 += k1 + 3u;
  for (int i = 0; i < 4; i++) { x0 += x1; x1 = rotl32(x1, rb[i]); x1 ^= x0; }
  x0 += k1;  x1 += ks2 + 4u;
  for (int i = 0; i < 4; i++) { x0 += x1; x1 = rotl32(x1, ra[i]); x1 ^= x0; }
  x0 += ks2; x1 += k0 + 5u;
  return {x0, x1};
}
// JAX threefry_partitionable 32-bit draw: bits(j) = out0 ^ out1 of tf(key, 0, j)
__device__ __forceinline__ unsigned tf_bits32(unsigned k0, unsigned k1,
                                              unsigned j) {
  TF2 r = threefry(k0, k1, 0u, j);
  return r.a ^ r.b;
}

__device__ __forceinline__ double waveReduceAdd64(double v) {
#pragma unroll
  for (int m = 32; m; m >>= 1) v += __shfl_xor(v, m, 64);
  return v;
}

// ---------------- split-K GEMM: P[m*Ndim+n] += A[64x(KT*64)] @ W  (fp64) ---
// grid (Ndim/64, 512/64, Kdim/(KT*64)), 256 thr. P pre-zeroed; unsafeAtomicAdd.
template <int KT>
__global__ __launch_bounds__(256) void gemm_split(
    const float* __restrict__ A, const float* __restrict__ W,
    double* __restrict__ P, int lda, int Ndim) {
  __shared__ float As[64][68];   // [m][k] pad->68 keeps b128 conflict-free
  __shared__ float Bs[64][64];   // [k][n]
  const int t = threadIdx.x;
  const int n0 = blockIdx.x * 64, m0 = blockIdx.y * 64;
  const int kbase = blockIdx.z * (KT * 64);
  const int tx = t & 15, ty = t >> 4;
  float4 ar[4], br[4];
  int mi[4], ki[4];
#pragma unroll
  for (int i = 0; i < 4; i++) {
    int idx = i * 256 + t;
    mi[i] = idx >> 4;               // 0..63
    ki[i] = (idx & 15) * 4;         // 0..60
  }
  auto load_tile = [&](int k0) {
#pragma unroll
    for (int i = 0; i < 4; i++) {
      ar[i] = *(const float4*)&A[(m0 + mi[i]) * lda + k0 + ki[i]];
      br[i] = *(const float4*)&W[(k0 + mi[i]) * Ndim + n0 + ki[i]];
    }
  };
  auto store_tile = [&]() {
#pragma unroll
    for (int i = 0; i < 4; i++) {
      *(float4*)&As[mi[i]][ki[i]] = ar[i];
      *(float4*)&Bs[mi[i]][ki[i]] = br[i];
    }
  };
  double acc[4][4] = {};
  load_tile(kbase);
  store_tile();
  __syncthreads();
  for (int kt = 0; kt < KT; kt++) {
    if (kt + 1 < KT) load_tile(kbase + (kt + 1) * 64);
#pragma unroll 4
    for (int kk = 0; kk < 64; kk++) {
      double a0 = (double)As[ty * 4 + 0][kk];
      double a1 = (double)As[ty * 4 + 1][kk];
      double a2 = (double)As[ty * 4 + 2][kk];
      double a3 = (double)As[ty * 4 + 3][kk];
      float4 bf = *(const float4*)&Bs[kk][tx * 4];
      double b0 = (double)bf.x, b1 = (double)bf.y;
      double b2 = (double)bf.z, b3 = (double)bf.w;
      acc[0][0] += a0 * b0; acc[0][1] += a0 * b1;
      acc[0][2] += a0 * b2; acc[0][3] += a0 * b3;
      acc[1][0] += a1 * b0; acc[1][1] += a1 * b1;
      acc[1][2] += a1 * b2; acc[1][3] += a1 * b3;
      acc[2][0] += a2 * b0; acc[2][1] += a2 * b1;
      acc[2][2] += a2 * b2; acc[2][3] += a2 * b3;
      acc[3][0] += a3 * b0; acc[3][1] += a3 * b1;
      acc[3][2] += a3 * b2; acc[3][3] += a3 * b3;
    }
    if (kt + 1 < KT) {
      __syncthreads();
      store_tile();
      __syncthreads();
    }
  }
#pragma unroll
  for (int i = 0; i < 4; i++)
#pragma unroll
    for (int j = 0; j < 4; j++)
      unsafeAtomicAdd(&P[(m0 + ty * 4 + i) * Ndim + n0 + tx * 4 + j],
                      acc[i][j]);
}

// ---------------- kv projection: 64 batched [512x64xK=512] GEMMs, no split --
// grid (64, 8): x = is_v*32 + l*8 + h, y = m-tile
__global__ __launch_bounds__(256) void kv_gemm(
    const float* __restrict__ flow, const float* __restrict__ Wk,
    const float* __restrict__ bk, const float* __restrict__ Wv,
    const float* __restrict__ bv, float* __restrict__ keys,
    float* __restrict__ vals) {
  __shared__ float As[64][68];
  __shared__ float Bs[64][64];
  const int t = threadIdx.x;
  const int sel = blockIdx.x;
  const int is_v = sel >> 5;
  const int lh = sel & 31;
  const int l = lh >> 3, h = lh & 7;
  const float* W  = (is_v ? Wv : Wk) + lh * (E * D);
  const float* bb = (is_v ? bv : bk) + lh * D;
  float* outp = is_v ? vals : keys;
  const int m0 = blockIdx.y * 64;
  const int tx = t & 15, ty = t >> 4;
  float4 ar[4], br[4];
  int mi[4], ki[4];
#pragma unroll
  for (int i = 0; i < 4; i++) {
    int idx = i * 256 + t;
    mi[i] = idx >> 4;
    ki[i] = (idx & 15) * 4;
  }
  auto load_tile = [&](int k0) {
#pragma unroll
    for (int i = 0; i < 4; i++) {
      ar[i] = *(const float4*)&flow[(m0 + mi[i]) * E + k0 + ki[i]];
      br[i] = *(const float4*)&W[(k0 + mi[i]) * D + ki[i]];
    }
  };
  auto store_tile = [&]() {
#pragma unroll
    for (int i = 0; i < 4; i++) {
      *(float4*)&As[mi[i]][ki[i]] = ar[i];
      *(float4*)&Bs[mi[i]][ki[i]] = br[i];
    }
  };
  double acc[4][4] = {};
  load_tile(0);
  store_tile();
  __syncthreads();
  constexpr int KT = E / 64;   // 8
  for (int kt = 0; kt < KT; kt++) {
    if (kt + 1 < KT) load_tile((kt + 1) * 64);
#pragma unroll 4
    for (int kk = 0; kk < 64; kk++) {
      double a0 = (double)As[ty * 4 + 0][kk];
      double a1 = (double)As[ty * 4 + 1][kk];
      double a2 = (double)As[ty * 4 + 2][kk];
      double a3 = (double)As[ty * 4 + 3][kk];
      float4 bf = *(const float4*)&Bs[kk][tx * 4];
      double b0 = (double)bf.x, b1 = (double)bf.y;
      double b2 = (double)bf.z, b3 = (double)bf.w;
      acc[0][0] += a0 * b0; acc[0][1] += a0 * b1;
      acc[0][2] += a0 * b2; acc[0][3] += a0 * b3;
      acc[1][0] += a1 * b0; acc[1][1] += a1 * b1;
      acc[1][2] += a1 * b2; acc[1][3] += a1 * b3;
      acc[2][0] += a2 * b0; acc[2][1] += a2 * b1;
      acc[2][2] += a2 * b2; acc[2][3] += a2 * b3;
      acc[3][0] += a3 * b0; acc[3][1] += a3 * b1;
      acc[3][2] += a3 * b2; acc[3][3] += a3 * b3;
    }
    if (kt + 1 < KT) {
      __syncthreads();
      store_tile();
      __syncthreads();
    }
  }
#pragma unroll
  for (int i = 0; i < 4; i++)
#pragma unroll
    for (int j = 0; j < 4; j++) {
      int m = m0 + ty * 4 + i;          // row = b*64 + v
      int d = tx * 4 + j;
      int b_ = m >> 6, v_ = m & 63;
      float out = (float)(acc[i][j] + (double)bb[d]);
      outp[(((l * B + b_) * H + h) * V + v_) * D + d] = out;
    }
}

// ---------------- epilogue: out = f32(P + bias), opt ReLU; P <- 0 ----------
__global__ __launch_bounds__(256) void epi_kernel(
    double* __restrict__ P, const float* __restrict__ bias,
    float* __restrict__ out, int nmask, int relu) {
  const int base = (blockIdx.x * 256 + threadIdx.x) * 4;
#pragma unroll
  for (int j = 0; j < 4; j++) {
    int idx = base + j;
    float f = (float)(P[idx] + (double)bias[idx & nmask]);
    if (relu) f = fmaxf(f, 0.0f);
    out[idx] = f;
    P[idx] = 0.0;
  }
}

// ---------------- zero P ----------------
__global__ __launch_bounds__(256) void zero_kernel(double* __restrict__ P) {
  const int base = (blockIdx.x * 256 + threadIdx.x) * 4;
#pragma unroll
  for (int j = 0; j < 4; j++) P[base + j] = 0.0;
}

// ---------------- fused attention + residual + LN1 (one block per row) -----
__global__ __launch_bounds__(256) void attn_kernel(
    float* __restrict__ att, const float* __restrict__ keys,
    const float* __restrict__ vals, const float* __restrict__ g,
    const float* __restrict__ bb, int l) {
  __shared__ float q[HD];
  __shared__ float sp[HD];
  __shared__ double rb[8];
  const int t = threadIdx.x;
  const int row = blockIdx.x;
  const int b_ = row >> 6;
  q[t]       = att[row * HD + t];
  q[t + 256] = att[row * HD + 256 + t];
  __syncthreads();
#pragma unroll
  for (int rep = 0; rep < 2; rep++) {
    int idx = t + rep * 256;
    int h = idx >> 6, w = idx & 63;
    const float* kp = keys + (((l * B + b_) * H + h) * V + w) * D;
    const float* qp = q + h * D;
    double s = 0.0;
#pragma unroll 8
    for (int d = 0; d < 64; d++) s += (double)qp[d] * (double)kp[d];
    sp[idx] = (float)s * 0.125f;
  }
  __syncthreads();
  {
    int h = t >> 5, w0 = t & 31;
    float s0 = sp[h * 64 + w0], s1 = sp[h * 64 + w0 + 32];
    float mx = fmaxf(s0, s1);
#pragma unroll
    for (int m = 16; m; m >>= 1) mx = fmaxf(mx, __shfl_xor(mx, m, 32));
    float e0 = expf(s0 - mx), e1 = expf(s1 - mx);
    double sm = (double)e0 + (double)e1;
#pragma unroll
    for (int m = 16; m; m >>= 1) sm += __shfl_xor(sm, m, 32);
    sp[h * 64 + w0]      = (float)((double)e0 / sm);
    sp[h * 64 + w0 + 32] = (float)((double)e1 / sm);
  }
  __syncthreads();
  float x[2];
#pragma unroll
  for (int rep = 0; rep < 2; rep++) {
    int idx = t + rep * 256;
    int h = idx >> 6, d = idx & 63;
    const float* vp = vals + (((l * B + b_) * H + h) * V) * D + d;
    const float* pp = sp + h * 64;
    double a = 0.0;
#pragma unroll 8
    for (int w = 0; w < 64; w++) a += (double)pp[w] * (double)vp[w * 64];
    x[rep] = q[idx] + (float)a;
  }
  double s1 = (double)x[0] + (double)x[1];
  double s2 = (double)x[0] * (double)x[0] + (double)x[1] * (double)x[1];
  s1 = waveReduceAdd64(s1);
  s2 = waveReduceAdd64(s2);
  const int wid = t >> 6, lane = t & 63;
  if (lane == 0) { rb[wid] = s1; rb[4 + wid] = s2; }
  __syncthreads();
  double S1 = rb[0] + rb[1] + rb[2] + rb[3];
  double S2 = rb[4] + rb[5] + rb[6] + rb[7];
  double mean = S1 / (double)HD;
  double var  = S2 / (double)HD - mean * mean;
  double inv  = 1.0 / sqrt(var + (double)1e-5f);
  att[row * HD + t] =
      (float)(((double)x[0] - mean) * inv * (double)g[t] + (double)bb[t]);
  att[row * HD + 256 + t] =
      (float)(((double)x[1] - mean) * inv * (double)g[t + 256] + (double)bb[t + 256]);
}

// ---------------- residual + LN2, consuming fp64 partial P (h = P + b3) ----
__global__ __launch_bounds__(256) void ln_res_P(
    float* __restrict__ att, double* __restrict__ P,
    const float* __restrict__ b3, const float* __restrict__ g,
    const float* __restrict__ bb) {
  __shared__ double rb[8];
  const int t = threadIdx.x;
  const int row = blockIdx.x;
  float h0 = (float)(P[row * HD + t] + (double)b3[t]);
  float h1v = (float)(P[row * HD + 256 + t] + (double)b3[t + 256]);
  float x0 = att[row * HD + t] + h0;
  float x1 = att[row * HD + 256 + t] + h1v;
  P[row * HD + t] = 0.0;
  P[row * HD + 256 + t] = 0.0;
  double s1 = (double)x0 + (double)x1;
  double s2 = (double)x0 * (double)x0 + (double)x1 * (double)x1;
  s1 = waveReduceAdd64(s1);
  s2 = waveReduceAdd64(s2);
  const int wid = t >> 6, lane = t & 63;
  if (lane == 0) { rb[wid] = s1; rb[4 + wid] = s2; }
  __syncthreads();
  double S1 = rb[0] + rb[1] + rb[2] + rb[3];
  double S2 = rb[4] + rb[5] + rb[6] + rb[7];
  double mean = S1 / (double)HD;
  double var  = S2 / (double)HD - mean * mean;
  double inv  = 1.0 / sqrt(var + (double)1e-5f);
  att[row * HD + t] =
      (float)(((double)x0 - mean) * inv * (double)g[t] + (double)bb[t]);
  att[row * HD + 256 + t] =
      (float)(((double)x1 - mean) * inv * (double)g[t + 256] + (double)bb[t + 256]);
}

// ---------------- gumbel-argmax sampling (one wave per sample row) ---------
__global__ __launch_bounds__(256) void sample_kernel(
    const float* __restrict__ logits, float* __restrict__ out) {
  constexpr TF2 KC = threefry(0u, 1u, 0u, 0u);  // fold_in(key(1), 0)
  constexpr TF2 KU = threefry(0u, 1u, 0u, 1u);  // fold_in(key(1), 1)
  const int lane = threadIdx.x & 63;
  const int wid = threadIdx.x >> 6;
  const int row = blockIdx.x * 4 + wid;
  const float* lrow = logits + (row >> 5) * R;
  float bvv = -1e30f;
  int bi = 0;
#pragma unroll
  for (int rep = 0; rep < 2; rep++) {
    int r = lane + rep * 64;
    unsigned j = (unsigned)row * (unsigned)R + (unsigned)r;
    unsigned bits = tf_bits32(KC.a, KC.b, j);
    float f = __uint_as_float((bits >> 9) | 0x3f800000u) - 1.0f;
    float u = fmaxf(f, 1.17549435e-38f);
    float gv = -logf(-logf(u));
    float v = lrow[r] + gv;
    if (v > bvv) { bvv = v; bi = r; }
  }
#pragma unroll
  for (int m = 32; m; m >>= 1) {
    float ov = __shfl_xor(bvv, m, 64);
    int oi = __shfl_xor(bi, m, 64);
    if (ov > bvv || (ov == bvv && oi < bi)) { bvv = ov; bi = oi; }
  }
  if (lane == 0) {
    unsigned ub = tf_bits32(KU.a, KU.b, (unsigned)row);
    float u = __uint_as_float((ub >> 9) | 0x3f800000u) - 1.0f;
    out[row] = ((float)bi + u) * (1.0f / 128.0f);
  }
}

// ---------------- launcher ----------------
extern "C" void kernel_launch(void* const* d_in, const int* in_sizes, int n_in,
                              void* d_out, int out_size, void* d_ws,
                              size_t ws_size, hipStream_t stream) {
  (void)in_sizes; (void)n_in; (void)out_size; (void)ws_size;
  const float* flow = (const float*)d_in[0];
  const float* Wsh  = (const float*)d_in[1];
  const float* bsh  = (const float*)d_in[2];
  const float* Wk   = (const float*)d_in[3];
  const float* bk   = (const float*)d_in[4];
  const float* Wv   = (const float*)d_in[5];
  const float* bv   = (const float*)d_in[6];
  const float* ln1g = (const float*)d_in[7];
  const float* ln1b = (const float*)d_in[8];
  const float* W1   = (const float*)d_in[9];
  const float* b1   = (const float*)d_in[10];
  const float* W2   = (const float*)d_in[11];
  const float* b2   = (const float*)d_in[12];
  const float* W3   = (const float*)d_in[13];
  const float* b3   = (const float*)d_in[14];
  const float* ln2g = (const float*)d_in[15];
  const float* ln2b = (const float*)d_in[16];
  const float* Wd   = (const float*)d_in[17];
  const float* bd   = (const float*)d_in[18];

  double* P = (double*)d_ws;                 // 512*1024 fp64 = 4 MB, reused
  float* fb = (float*)(P + ROWS * M);
  float* keys   = fb;                        // 1,048,576
  float* vals   = keys + L * B * H * V * D;  // 1,048,576
  float* att    = vals + L * B * H * V * D;  // 262,144
  float* h1     = att + ROWS * HD;           // 524,288
  float* h2     = h1 + ROWS * M;             // 524,288
  float* logits = h2 + ROWS * M;             // 65,536   (~18 MB total)

  zero_kernel<<<ROWS * M / 1024, 256, 0, stream>>>(P);
  kv_gemm<<<dim3(2 * L * H, ROWS / 64), 256, 0, stream>>>(flow, Wk, bk, Wv, bv,
                                                          keys, vals);
  // shift: [512x512] @ K=512, KT=2, split 4
  gemm_split<2><<<dim3(HD / 64, ROWS / 64, 4), 256, 0, stream>>>(
      flow, Wsh, P, E, HD);
  epi_kernel<<<ROWS * HD / 1024, 256, 0, stream>>>(P, bsh, att, HD - 1, 0);
  for (int l = 0; l < L; l++) {
    attn_kernel<<<ROWS, 256, 0, stream>>>(att, keys, vals, ln1g + l * HD,
                                          ln1b + l * HD, l);
    // W1: [512x1024] @ K=512, KT=2, split 4
    gemm_split<2><<<dim3(M / 64, ROWS / 64, 4), 256, 0, stream>>>(
        att, W1 + l * HD * M, P, HD, M);
    epi_kernel<<<ROWS * M / 1024, 256, 0, stream>>>(P, b1 + l * M, h1, M - 1, 1);
    // W2: [512x1024] @ K=1024, KT=4, split 4
    gemm_split<4><<<dim3(M / 64, ROWS / 64, 4), 256, 0, stream>>>(
        h1, W2 + l * M * M, P, M, M);
    epi_kernel<<<ROWS * M / 1024, 256, 0, stream>>>(P, b2 + l * M, h2, M - 1, 1);
    // W3: [512x512] @ K=1024, KT=4, split 4
    gemm_split<4><<<dim3(HD / 64, ROWS / 64, 4), 256, 0, stream>>>(
        h2, W3 + l * M * HD, P, M, HD);
    ln_res_P<<<ROWS, 256, 0, stream>>>(att, P, b3 + l * HD, ln2g + l * HD,
                                       ln2b + l * HD);
  }
  // dist: [512x128] @ K=512, KT=1, split 8
  gemm_split<1><<<dim3(R / 64, ROWS / 64, 8), 256, 0, stream>>>(
      att, Wd, P, HD, R);
  epi_kernel<<<ROWS * R / 1024, 256, 0, stream>>>(P, bd, logits, R - 1, 0);
  sample_kernel<<<SROWS / 4, 256, 0, stream>>>(logits, (float*)d_out);
}

// Round 4
// 734.782 us; speedup vs baseline: 2.7072x; 1.6265x over previous
//
#include <hip/hip_runtime.h>
#include <hip/hip_bf16.h>
#include <math.h>

// ---------------- problem dims (fixed by setup_inputs) ----------------
constexpr int B  = 8,  V = 64, E = 512, NS = 32;
constexpr int L  = 4,  H = 8,  D = 64,  M  = 1024, R = 128;
constexpr int HD = H * D;            // 512
constexpr int ROWS  = B * V;         // 512 distinct transformer rows
constexpr int SROWS = ROWS * NS;     // 16384 sample rows

typedef _Float16 half8 __attribute__((ext_vector_type(8)));
typedef float floatx4 __attribute__((ext_vector_type(4)));

// ---------------- threefry2x32-20 (JAX-compatible, partitionable) ----------
struct TF2 { unsigned a, b; };
__host__ __device__ constexpr unsigned rotl32(unsigned x, int d) {
  return (x << d) | (x >> (32 - d));
}
__host__ __device__ constexpr TF2 threefry(unsigned k0, unsigned k1,
                                           unsigned x0, unsigned x1) {
  unsigned ks2 = k0 ^ k1 ^ 0x1BD11BDAu;
  x0 += k0; x1 += k1;
  const int ra[4] = {13, 15, 26, 6};
  const int rb[4] = {17, 29, 16, 24};
  for (int i = 0; i < 4; i++) { x0 += x1; x1 = rotl32(x1, ra[i]); x1 ^= x0; }
  x0 += k1;  x1 += ks2 + 1u;
  for (int i = 0; i < 4; i++) { x0 += x1; x1 = rotl32(x1, rb[i]); x1 ^= x0; }
  x0 += ks2; x1 += k0 + 2u;
  for (int i = 0; i < 4; i++) { x0 += x1; x1 = rotl32(x1, ra[i]); x1 ^= x0; }
  x0 += k0;  x1 += k1 + 3u;
  for (int i = 0; i < 4; i++) { x0 += x1; x1 = rotl32(x1, rb[i]); x1 ^= x0; }
  x0 += k1;  x1 += ks2 + 4u;
  for (int i = 0; i < 4; i++) { x0 += x1; x1 = rotl32(x1, ra[i]); x1 ^= x0; }
  x0 += ks2; x1 += k0 + 5u;
  return {x0, x1};
}
__device__ __forceinline__ unsigned tf_bits32(unsigned k0, unsigned k1,
                                              unsigned j) {
  TF2 r = threefry(k0, k1, 0u, j);
  return r.a ^ r.b;
}

__device__ __forceinline__ double waveReduceAdd64(double v) {
#pragma unroll
  for (int m = 32; m; m >>= 1) v += __shfl_xor(v, m, 64);
  return v;
}

__device__ __forceinline__ void split16(float v, _Float16& h, _Float16& l) {
  h = (_Float16)v;
  l = (_Float16)((v - (float)h) * 2048.0f);
}

// ---------------- weight transpose + split: W[K][N] -> Wt_h/Wt_l[N][K] -----
__global__ __launch_bounds__(256) void wsplit(const float* __restrict__ src,
                                              _Float16* __restrict__ dh,
                                              _Float16* __restrict__ dl,
                                              int K, int N) {
  __shared__ float tile[64][65];
  const int t = threadIdx.x;
  const size_t moff = (size_t)blockIdx.z * K * N;
  src += moff; dh += moff; dl += moff;
  const int k0 = blockIdx.x * 64, n0 = blockIdx.y * 64;
#pragma unroll
  for (int i = 0; i < 16; i++) {
    int idx = i * 256 + t, r = idx >> 6, c = idx & 63;
    tile[r][c] = src[(size_t)(k0 + r) * N + n0 + c];
  }
  __syncthreads();
#pragma unroll
  for (int i = 0; i < 16; i++) {
    int idx = i * 256 + t, n = idx >> 6, k = idx & 63;
    float v = tile[k][n];
    _Float16 h, l;
    split16(v, h, l);
    dh[(size_t)(n0 + n) * K + k0 + k] = h;
    dl[(size_t)(n0 + n) * K + k0 + k] = l;
  }
}

// ---------------- elementwise split (A-side, flow) ----------------
__global__ __launch_bounds__(256) void asplit(const float* __restrict__ src,
                                              _Float16* __restrict__ dh,
                                              _Float16* __restrict__ dl) {
  const int base = (blockIdx.x * 256 + threadIdx.x) * 4;
  float4 v = *(const float4*)&src[base];
  float a[4] = {v.x, v.y, v.z, v.w};
#pragma unroll
  for (int j = 0; j < 4; j++) {
    _Float16 h, l;
    split16(a[j], h, l);
    dh[base + j] = h;
    dl[base + j] = l;
  }
}

// ---------------- 64x64 MFMA GEMM core (fp16 split, 3-term) ----------------
// A_h/A_l: [M][K] row-major fp16 (pre-offset to m0). B_h/B_l: [N][K] (pre-
// offset to n0). LDS buffer: 2 bufs x 4 arrays x 64x32 fp16 = 32 KB.
// Wave layout: wave w -> (wm,wn) = (w>>1, w&1); 2x2 tiles of 16x16 each.
// Fragment layouts (verified m89/m120): A[m=lane&15][k=quad*8+j],
// B_t rows are n so same addressing; C/D: col=lane&15, row=quad*4+reg.
struct Acc {
  floatx4 hh[2][2];
  floatx4 mid[2][2];
};

__device__ __forceinline__ void gemm64_core(
    _Float16* lds, const _Float16* __restrict__ pAh,
    const _Float16* __restrict__ pAl, const _Float16* __restrict__ pBh,
    const _Float16* __restrict__ pBl, int K, Acc& acc) {
  const int t = threadIdx.x;
  const int lane = t & 63, wave = t >> 6;
  const int wm = wave >> 1, wn = wave & 1;
  const int quad = lane >> 4, l15 = lane & 15;
  const int srow = t >> 2, skoff = (t & 3) * 8;
  const int KT = K >> 5;
#pragma unroll
  for (int mi = 0; mi < 2; mi++)
#pragma unroll
    for (int ni = 0; ni < 2; ni++) {
      acc.hh[mi][ni] = (floatx4){0.f, 0.f, 0.f, 0.f};
      acc.mid[mi][ni] = (floatx4){0.f, 0.f, 0.f, 0.f};
    }
  uint4 rg[4];
  auto load = [&](int kt) {
    const size_t off = (size_t)srow * K + kt * 32 + skoff;
    rg[0] = *(const uint4*)&pAh[off];
    rg[1] = *(const uint4*)&pAl[off];
    rg[2] = *(const uint4*)&pBh[off];
    rg[3] = *(const uint4*)&pBl[off];
  };
  auto store = [&](int buf) {
    const int off = srow * 32 + skoff;
#pragma unroll
    for (int a = 0; a < 4; a++)
      *(uint4*)&lds[(buf * 4 + a) * 2048 + off] = rg[a];
  };
  load(0);
  store(0);
  for (int kt = 0; kt < KT; kt++) {
    __syncthreads();
    if (kt + 1 < KT) load(kt + 1);
    const int buf = kt & 1;
    half8 Af[2][2], Bf[2][2];  // [h/l][tile]
#pragma unroll
    for (int mi = 0; mi < 2; mi++) {
      int arow = (wm * 32 + mi * 16 + l15) * 32 + quad * 8;
      int brow = (wn * 32 + mi * 16 + l15) * 32 + quad * 8;
      Af[0][mi] = *(const half8*)&lds[(buf * 4 + 0) * 2048 + arow];
      Af[1][mi] = *(const half8*)&lds[(buf * 4 + 1) * 2048 + arow];
      Bf[0][mi] = *(const half8*)&lds[(buf * 4 + 2) * 2048 + brow];
      Bf[1][mi] = *(const half8*)&lds[(buf * 4 + 3) * 2048 + brow];
    }
#pragma unroll
    for (int mi = 0; mi < 2; mi++)
#pragma unroll
      for (int ni = 0; ni < 2; ni++) {
        acc.hh[mi][ni] = __builtin_amdgcn_mfma_f32_16x16x32_f16(
            Af[0][mi], Bf[0][ni], acc.hh[mi][ni], 0, 0, 0);
        acc.mid[mi][ni] = __builtin_amdgcn_mfma_f32_16x16x32_f16(
            Af[0][mi], Bf[1][ni], acc.mid[mi][ni], 0, 0, 0);
        acc.mid[mi][ni] = __builtin_amdgcn_mfma_f32_16x16x32_f16(
            Af[1][mi], Bf[0][ni], acc.mid[mi][ni], 0, 0, 0);
      }
    if (kt + 1 < KT) store((kt + 1) & 1);
  }
}

// ---------------- generic GEMM: C = A @ B_t^T + bias (opt relu/split out) --
__global__ __launch_bounds__(256) void mfma_gemm(
    const _Float16* __restrict__ Ah, const _Float16* __restrict__ Al,
    const _Float16* __restrict__ Bh, const _Float16* __restrict__ Bl,
    const float* __restrict__ bias, float* __restrict__ Cf,
    _Float16* __restrict__ Oh, _Float16* __restrict__ Ol, int K, int Ndim,
    int relu) {
  __shared__ _Float16 lds[2 * 4 * 2048];
  const int m0 = blockIdx.x * 64, n0 = blockIdx.y * 64;
  Acc acc;
  gemm64_core(lds, Ah + (size_t)m0 * K, Al + (size_t)m0 * K,
              Bh + (size_t)n0 * K, Bl + (size_t)n0 * K, K, acc);
  const int t = threadIdx.x, lane = t & 63, wave = t >> 6;
  const int wm = wave >> 1, wn = wave & 1, quad = lane >> 4, l15 = lane & 15;
#pragma unroll
  for (int mi = 0; mi < 2; mi++)
#pragma unroll
    for (int ni = 0; ni < 2; ni++)
#pragma unroll
      for (int r = 0; r < 4; r++) {
        float v = acc.hh[mi][ni][r] + acc.mid[mi][ni][r] * (1.0f / 2048.0f);
        int m = m0 + wm * 32 + mi * 16 + quad * 4 + r;
        int n = n0 + wn * 32 + ni * 16 + l15;
        v += bias[n];
        if (relu) v = fmaxf(v, 0.0f);
        if (Cf) Cf[(size_t)m * Ndim + n] = v;
        if (Oh) {
          _Float16 h, l;
          split16(v, h, l);
          Oh[(size_t)m * Ndim + n] = h;
          Ol[(size_t)m * Ndim + n] = l;
        }
      }
}

// ---------------- kv projection via MFMA: 64 batched [512x64x512] ----------
__global__ __launch_bounds__(256) void kv_mfma(
    const _Float16* __restrict__ Fh, const _Float16* __restrict__ Fl,
    const _Float16* __restrict__ Wkh, const _Float16* __restrict__ Wkl,
    const _Float16* __restrict__ Wvh, const _Float16* __restrict__ Wvl,
    const float* __restrict__ bk, const float* __restrict__ bv,
    float* __restrict__ keys, float* __restrict__ vals) {
  __shared__ _Float16 lds[2 * 4 * 2048];
  const int m0 = blockIdx.x * 64;
  const int lh = blockIdx.y;       // l*8 + h
  const int is_v = blockIdx.z;
  const _Float16* Bh = (is_v ? Wvh : Wkh) + (size_t)lh * D * E;
  const _Float16* Bl = (is_v ? Wvl : Wkl) + (size_t)lh * D * E;
  const float* bb = (is_v ? bv : bk) + lh * D;
  float* outp = is_v ? vals : keys;
  const int l = lh >> 3, h = lh & 7;
  Acc acc;
  gemm64_core(lds, Fh + (size_t)m0 * E, Fl + (size_t)m0 * E, Bh, Bl, E, acc);
  const int t = threadIdx.x, lane = t & 63, wave = t >> 6;
  const int wm = wave >> 1, wn = wave & 1, quad = lane >> 4, l15 = lane & 15;
#pragma unroll
  for (int mi = 0; mi < 2; mi++)
#pragma unroll
    for (int ni = 0; ni < 2; ni++)
#pragma unroll
      for (int r = 0; r < 4; r++) {
        float v = acc.hh[mi][ni][r] + acc.mid[mi][ni][r] * (1.0f / 2048.0f);
        int m = m0 + wm * 32 + mi * 16 + quad * 4 + r;  // row = b*64 + v
        int n = wn * 32 + ni * 16 + l15;                // d
        v += bb[n];
        int b_ = m >> 6, v_ = m & 63;
        outp[(((size_t)(l * B + b_) * H + h) * V + v_) * D + n] = v;
      }
}

// ---------------- fused attention + residual + LN1 (one block per row) -----
__global__ __launch_bounds__(256) void attn_kernel(
    float* __restrict__ att, _Float16* __restrict__ att_h,
    _Float16* __restrict__ att_l, const float* __restrict__ keys,
    const float* __restrict__ vals, const float* __restrict__ g,
    const float* __restrict__ bb, int l) {
  __shared__ float q[HD];
  __shared__ float sp[HD];
  __shared__ double rb[8];
  const int t = threadIdx.x;
  const int row = blockIdx.x;
  const int b_ = row >> 6;
  q[t]       = att[row * HD + t];
  q[t + 256] = att[row * HD + 256 + t];
  __syncthreads();
#pragma unroll
  for (int rep = 0; rep < 2; rep++) {
    int idx = t + rep * 256;
    int h = idx >> 6, w = idx & 63;
    const float* kp = keys + (((size_t)(l * B + b_) * H + h) * V + w) * D;
    const float* qp = q + h * D;
    double s = 0.0;
#pragma unroll 8
    for (int d = 0; d < 64; d++) s += (double)qp[d] * (double)kp[d];
    sp[idx] = (float)s * 0.125f;
  }
  __syncthreads();
  {
    int h = t >> 5, w0 = t & 31;
    float s0 = sp[h * 64 + w0], s1 = sp[h * 64 + w0 + 32];
    float mx = fmaxf(s0, s1);
#pragma unroll
    for (int m = 16; m; m >>= 1) mx = fmaxf(mx, __shfl_xor(mx, m, 32));
    float e0 = expf(s0 - mx), e1 = expf(s1 - mx);
    double sm = (double)e0 + (double)e1;
#pragma unroll
    for (int m = 16; m; m >>= 1) sm += __shfl_xor(sm, m, 32);
    sp[h * 64 + w0]      = (float)((double)e0 / sm);
    sp[h * 64 + w0 + 32] = (float)((double)e1 / sm);
  }
  __syncthreads();
  float x[2];
#pragma unroll
  for (int rep = 0; rep < 2; rep++) {
    int idx = t + rep * 256;
    int h = idx >> 6, d = idx & 63;
    const float* vp = vals + (((size_t)(l * B + b_) * H + h) * V) * D + d;
    const float* pp = sp + h * 64;
    double a = 0.0;
#pragma unroll 8
    for (int w = 0; w < 64; w++) a += (double)pp[w] * (double)vp[w * 64];
    x[rep] = q[idx] + (float)a;
  }
  double s1 = (double)x[0] + (double)x[1];
  double s2 = (double)x[0] * (double)x[0] + (double)x[1] * (double)x[1];
  s1 = waveReduceAdd64(s1);
  s2 = waveReduceAdd64(s2);
  const int wid = t >> 6, lane = t & 63;
  if (lane == 0) { rb[wid] = s1; rb[4 + wid] = s2; }
  __syncthreads();
  double S1 = rb[0] + rb[1] + rb[2] + rb[3];
  double S2 = rb[4] + rb[5] + rb[6] + rb[7];
  double mean = S1 / (double)HD;
  double var  = S2 / (double)HD - mean * mean;
  double inv  = 1.0 / sqrt(var + (double)1e-5f);
  float y0 =
      (float)(((double)x[0] - mean) * inv * (double)g[t] + (double)bb[t]);
  float y1 = (float)(((double)x[1] - mean) * inv * (double)g[t + 256] +
                     (double)bb[t + 256]);
  att[row * HD + t] = y0;
  att[row * HD + 256 + t] = y1;
  _Float16 h0, l0, h1v, l1v;
  split16(y0, h0, l0);
  split16(y1, h1v, l1v);
  att_h[row * HD + t] = h0;
  att_l[row * HD + t] = l0;
  att_h[row * HD + 256 + t] = h1v;
  att_l[row * HD + 256 + t] = l1v;
}

// ---------------- residual + LN2 (consumes f32 h3; writes att + split) -----
__global__ __launch_bounds__(256) void ln_res_kernel(
    float* __restrict__ att, _Float16* __restrict__ att_h,
    _Float16* __restrict__ att_l, const float* __restrict__ h3,
    const float* __restrict__ g, const float* __restrict__ bb) {
  __shared__ double rb[8];
  const int t = threadIdx.x;
  const int row = blockIdx.x;
  float x0 = att[row * HD + t] + h3[row * HD + t];
  float x1 = att[row * HD + 256 + t] + h3[row * HD + 256 + t];
  double s1 = (double)x0 + (double)x1;
  double s2 = (double)x0 * (double)x0 + (double)x1 * (double)x1;
  s1 = waveReduceAdd64(s1);
  s2 = waveReduceAdd64(s2);
  const int wid = t >> 6, lane = t & 63;
  if (lane == 0) { rb[wid] = s1; rb[4 + wid] = s2; }
  __syncthreads();
  double S1 = rb[0] + rb[1] + rb[2] + rb[3];
  double S2 = rb[4] + rb[5] + rb[6] + rb[7];
  double mean = S1 / (double)HD;
  double var  = S2 / (double)HD - mean * mean;
  double inv  = 1.0 / sqrt(var + (double)1e-5f);
  float y0 = (float)(((double)x0 - mean) * inv * (double)g[t] + (double)bb[t]);
  float y1 = (float)(((double)x1 - mean) * inv * (double)g[t + 256] +
                     (double)bb[t + 256]);
  att[row * HD + t] = y0;
  att[row * HD + 256 + t] = y1;
  _Float16 h0, l0, h1v, l1v;
  split16(y0, h0, l0);
  split16(y1, h1v, l1v);
  att_h[row * HD + t] = h0;
  att_l[row * HD + t] = l0;
  att_h[row * HD + 256 + t] = h1v;
  att_l[row * HD + 256 + t] = l1v;
}

// ---------------- gumbel-argmax sampling (bit-exact vs JAX; verified) ------
__global__ __launch_bounds__(256) void sample_kernel(
    const float* __restrict__ logits, float* __restrict__ out) {
  constexpr TF2 KC = threefry(0u, 1u, 0u, 0u);  // fold_in(key(1), 0)
  constexpr TF2 KU = threefry(0u, 1u, 0u, 1u);  // fold_in(key(1), 1)
  const int lane = threadIdx.x & 63;
  const int wid = threadIdx.x >> 6;
  const int row = blockIdx.x * 4 + wid;
  const float* lrow = logits + (row >> 5) * R;
  float bvv = -1e30f;
  int bi = 0;
#pragma unroll
  for (int rep = 0; rep < 2; rep++) {
    int r = lane + rep * 64;
    unsigned j = (unsigned)row * (unsigned)R + (unsigned)r;
    unsigned bits = tf_bits32(KC.a, KC.b, j);
    float f = __uint_as_float((bits >> 9) | 0x3f800000u) - 1.0f;
    float u = fmaxf(f, 1.17549435e-38f);
    float gv = -logf(-logf(u));
    float v = lrow[r] + gv;
    if (v > bvv) { bvv = v; bi = r; }
  }
#pragma unroll
  for (int m = 32; m; m >>= 1) {
    float ov = __shfl_xor(bvv, m, 64);
    int oi = __shfl_xor(bi, m, 64);
    if (ov > bvv || (ov == bvv && oi < bi)) { bvv = ov; bi = oi; }
  }
  if (lane == 0) {
    unsigned ub = tf_bits32(KU.a, KU.b, (unsigned)row);
    float u = __uint_as_float((ub >> 9) | 0x3f800000u) - 1.0f;
    out[row] = ((float)bi + u) * (1.0f / 128.0f);
  }
}

// ---------------- launcher ----------------
extern "C" void kernel_launch(void* const* d_in, const int* in_sizes, int n_in,
                              void* d_out, int out_size, void* d_ws,
                              size_t ws_size, hipStream_t stream) {
  (void)in_sizes; (void)n_in; (void)out_size; (void)ws_size;
  const float* flow = (const float*)d_in[0];
  const float* Wsh  = (const float*)d_in[1];
  const float* bsh  = (const float*)d_in[2];
  const float* Wk   = (const float*)d_in[3];
  const float* bk   = (const float*)d_in[4];
  const float* Wv   = (const float*)d_in[5];
  const float* bv   = (const float*)d_in[6];
  const float* ln1g = (const float*)d_in[7];
  const float* ln1b = (const float*)d_in[8];
  const float* W1   = (const float*)d_in[9];
  const float* b1   = (const float*)d_in[10];
  const float* W2   = (const float*)d_in[11];
  const float* b2   = (const float*)d_in[12];
  const float* W3   = (const float*)d_in[13];
  const float* b3   = (const float*)d_in[14];
  const float* ln2g = (const float*)d_in[15];
  const float* ln2b = (const float*)d_in[16];
  const float* Wd   = (const float*)d_in[17];
  const float* bd   = (const float*)d_in[18];

  // ---- workspace carve-up (f32 region then fp16 region; all 16B aligned) --
  float* ws = (float*)d_ws;
  float* keys   = ws;                         // 1,048,576 f32
  float* vals   = keys + 1048576;             // 1,048,576
  float* att    = vals + 1048576;             // 262,144
  float* h3     = att + 262144;               // 262,144
  float* logits = h3 + 262144;                // 65,536
  _Float16* hp = (_Float16*)(logits + 65536);
  _Float16* flow_h = hp;            hp += 262144;
  _Float16* flow_l = hp;            hp += 262144;
  _Float16* Wsh_h  = hp;            hp += 262144;
  _Float16* Wsh_l  = hp;            hp += 262144;
  _Float16* Wk_h   = hp;            hp += 1048576;
  _Float16* Wk_l   = hp;            hp += 1048576;
  _Float16* Wv_h   = hp;            hp += 1048576;
  _Float16* Wv_l   = hp;            hp += 1048576;
  _Float16* W1_h   = hp;            hp += 2097152;
  _Float16* W1_l   = hp;            hp += 2097152;
  _Float16* W2_h   = hp;            hp += 4194304;
  _Float16* W2_l   = hp;            hp += 4194304;
  _Float16* W3_h   = hp;            hp += 2097152;
  _Float16* W3_l   = hp;            hp += 2097152;
  _Float16* Wd_h   = hp;            hp += 65536;
  _Float16* Wd_l   = hp;            hp += 65536;
  _Float16* att_h  = hp;            hp += 262144;
  _Float16* att_l  = hp;            hp += 262144;
  _Float16* h1_h   = hp;            hp += 524288;
  _Float16* h1_l   = hp;            hp += 524288;
  _Float16* h2_h   = hp;            hp += 524288;
  _Float16* h2_l   = hp;            hp += 524288;   // ~60 MB total

  // ---- input splitting ----
  asplit<<<256, 256, 0, stream>>>(flow, flow_h, flow_l);
  wsplit<<<dim3(8, 8, 1),  256, 0, stream>>>(Wsh, Wsh_h, Wsh_l, 512, 512);
  wsplit<<<dim3(8, 1, 32), 256, 0, stream>>>(Wk, Wk_h, Wk_l, 512, 64);
  wsplit<<<dim3(8, 1, 32), 256, 0, stream>>>(Wv, Wv_h, Wv_l, 512, 64);
  wsplit<<<dim3(8, 16, 4), 256, 0, stream>>>(W1, W1_h, W1_l, 512, 1024);
  wsplit<<<dim3(16, 16, 4), 256, 0, stream>>>(W2, W2_h, W2_l, 1024, 1024);
  wsplit<<<dim3(16, 8, 4), 256, 0, stream>>>(W3, W3_h, W3_l, 1024, 512);
  wsplit<<<dim3(8, 2, 1),  256, 0, stream>>>(Wd, Wd_h, Wd_l, 512, 128);

  // ---- keys/vals + shift ----
  kv_mfma<<<dim3(8, 32, 2), 256, 0, stream>>>(flow_h, flow_l, Wk_h, Wk_l,
                                              Wv_h, Wv_l, bk, bv, keys, vals);
  mfma_gemm<<<dim3(8, 8), 256, 0, stream>>>(flow_h, flow_l, Wsh_h, Wsh_l, bsh,
                                            att, nullptr, nullptr, 512, 512,
                                            0);
  // ---- transformer layers ----
  for (int l = 0; l < L; l++) {
    attn_kernel<<<ROWS, 256, 0, stream>>>(att, att_h, att_l, keys, vals,
                                          ln1g + l * HD, ln1b + l * HD, l);
    mfma_gemm<<<dim3(8, 16), 256, 0, stream>>>(
        att_h, att_l, W1_h + (size_t)l * 524288, W1_l + (size_t)l * 524288,
        b1 + l * M, nullptr, h1_h, h1_l, 512, 1024, 1);
    mfma_gemm<<<dim3(8, 16), 256, 0, stream>>>(
        h1_h, h1_l, W2_h + (size_t)l * 1048576, W2_l + (size_t)l * 1048576,
        b2 + l * M, nullptr, h2_h, h2_l, 1024, 1024, 1);
    mfma_gemm<<<dim3(8, 8), 256, 0, stream>>>(
        h2_h, h2_l, W3_h + (size_t)l * 524288, W3_l + (size_t)l * 524288,
        b3 + l * HD, h3, nullptr, nullptr, 1024, 512, 0);
    ln_res_kernel<<<ROWS, 256, 0, stream>>>(att, att_h, att_l, h3,
                                            ln2g + l * HD, ln2b + l * HD);
  }
  // ---- distribution head + sampling ----
  mfma_gemm<<<dim3(8, 2), 256, 0, stream>>>(att_h, att_l, Wd_h, Wd_l, bd,
                                            logits, nullptr, nullptr, 512, 128,
                                            0);
  sample_kernel<<<SROWS / 4, 256, 0, stream>>>(logits, (float*)d_out);
}

// Round 5
// 598.843 us; speedup vs baseline: 3.3217x; 1.2270x over previous
//
#include <hip/hip_runtime.h>
#include <hip/hip_bf16.h>
#include <math.h>

// ---------------- problem dims (fixed by setup_inputs) ----------------
constexpr int B  = 8,  V = 64, E = 512, NS = 32;
constexpr int L  = 4,  H = 8,  D = 64,  M  = 1024, R = 128;
constexpr int HD = H * D;            // 512
constexpr int ROWS  = B * V;         // 512 distinct transformer rows
constexpr int SROWS = ROWS * NS;     // 16384 sample rows

typedef _Float16 half8 __attribute__((ext_vector_type(8)));
typedef float floatx4 __attribute__((ext_vector_type(4)));

// ---------------- threefry2x32-20 (JAX-compatible, partitionable) ----------
struct TF2 { unsigned a, b; };
__host__ __device__ constexpr unsigned rotl32(unsigned x, int d) {
  return (x << d) | (x >> (32 - d));
}
__host__ __device__ constexpr TF2 threefry(unsigned k0, unsigned k1,
                                           unsigned x0, unsigned x1) {
  unsigned ks2 = k0 ^ k1 ^ 0x1BD11BDAu;
  x0 += k0; x1 += k1;
  const int ra[4] = {13, 15, 26, 6};
  const int rb[4] = {17, 29, 16, 24};
  for (int i = 0; i < 4; i++) { x0 += x1; x1 = rotl32(x1, ra[i]); x1 ^= x0; }
  x0 += k1;  x1 += ks2 + 1u;
  for (int i = 0; i < 4; i++) { x0 += x1; x1 = rotl32(x1, rb[i]); x1 ^= x0; }
  x0 += ks2; x1 += k0 + 2u;
  for (int i = 0; i < 4; i++) { x0 += x1; x1 = rotl32(x1, ra[i]); x1 ^= x0; }
  x0 += k0;  x1 += k1 + 3u;
  for (int i = 0; i < 4; i++) { x0 += x1; x1 = rotl32(x1, rb[i]); x1 ^= x0; }
  x0 += k1;  x1 += ks2 + 4u;
  for (int i = 0; i < 4; i++) { x0 += x1; x1 = rotl32(x1, ra[i]); x1 ^= x0; }
  x0 += ks2; x1 += k0 + 5u;
  return {x0, x1};
}
__device__ __forceinline__ unsigned tf_bits32(unsigned k0, unsigned k1,
                                              unsigned j) {
  TF2 r = threefry(k0, k1, 0u, j);
  return r.a ^ r.b;
}

__device__ __forceinline__ double waveReduceAdd64(double v) {
#pragma unroll
  for (int m = 32; m; m >>= 1) v += __shfl_xor(v, m, 64);
  return v;
}

__device__ __forceinline__ void split16(float v, _Float16& h, _Float16& l) {
  h = (_Float16)v;
  l = (_Float16)((v - (float)h) * 2048.0f);
}

// ---------------- zero f32 region ----------------
__global__ __launch_bounds__(256) void zero_kernel(float* __restrict__ p) {
  const int base = (blockIdx.x * 256 + threadIdx.x) * 4;
#pragma unroll
  for (int j = 0; j < 4; j++) p[base + j] = 0.0f;
}

// ---------------- all-weights transpose + split in ONE launch --------------
struct WArgs {
  const float* s[7];
  _Float16* h[7];
  _Float16* l[7];
};
// matrices: 0 Wsh(512,512) 1 Wk(512,64)x32 2 Wv(512,64)x32 3 W1(512,1024)x4
//           4 W2(1024,1024)x4 5 W3(1024,512)x4 6 Wd(512,128)
__global__ __launch_bounds__(256) void wsplit_all(WArgs a) {
  const int WS_OFF[8] = {0, 64, 320, 576, 1088, 2112, 2624, 2640};
  const int WS_K[7] = {512, 512, 512, 512, 1024, 1024, 512};
  const int WS_N[7] = {512, 64, 64, 1024, 1024, 512, 128};
  __shared__ float tile[64][65];
  int bid = blockIdx.x;
  int mi = 0;
  while (bid >= WS_OFF[mi + 1]) mi++;
  int tt = bid - WS_OFF[mi];
  const int K = WS_K[mi], N = WS_N[mi];
  const int ktiles = K >> 6, ntiles = N >> 6;
  const int per = ktiles * ntiles;
  const int z = tt / per;
  const int rem = tt - z * per;
  const int k0 = (rem % ktiles) * 64, n0 = (rem / ktiles) * 64;
  const size_t moff = (size_t)z * K * N;
  const float* src = a.s[mi] + moff;
  _Float16* dh = a.h[mi] + moff;
  _Float16* dl = a.l[mi] + moff;
  const int t = threadIdx.x;
#pragma unroll
  for (int i = 0; i < 16; i++) {
    int idx = i * 256 + t, r = idx >> 6, c = idx & 63;
    tile[r][c] = src[(size_t)(k0 + r) * N + n0 + c];
  }
  __syncthreads();
#pragma unroll
  for (int i = 0; i < 16; i++) {
    int idx = i * 256 + t, n = idx >> 6, k = idx & 63;
    float v = tile[k][n];
    _Float16 h, l;
    split16(v, h, l);
    dh[(size_t)(n0 + n) * K + k0 + k] = h;
    dl[(size_t)(n0 + n) * K + k0 + k] = l;
  }
}

// ---------------- elementwise split (flow) ----------------
__global__ __launch_bounds__(256) void asplit(const float* __restrict__ src,
                                              _Float16* __restrict__ dh,
                                              _Float16* __restrict__ dl) {
  const int base = (blockIdx.x * 256 + threadIdx.x) * 4;
  float4 v = *(const float4*)&src[base];
  float a[4] = {v.x, v.y, v.z, v.w};
#pragma unroll
  for (int j = 0; j < 4; j++) {
    _Float16 h, l;
    split16(a[j], h, l);
    dh[base + j] = h;
    dl[base + j] = l;
  }
}

// ---------------- 32x64 MFMA GEMM, optional split-K (f32 atomic) -----------
// A_h/A_l: [M][K] fp16. B_h/B_l: [N][K] fp16 (transposed weights).
// Tile 32(m) x 64(n); 4 waves; wave w: m-tile (w>>1), n-tiles {2(w&1), +1}.
// LDS rows padded to 40 fp16 -> bank-conflict-free (2-way only).
// kz==1: full K, epilogue bias(+relu), stores f32 C and/or split Oh/Ol.
// kz>1 : K chunk per blockIdx.z, atomicAdd into pre-zeroed f32 C (bias @z=0).
__global__ __launch_bounds__(256) void mfma_gemm(
    const _Float16* __restrict__ Ah, const _Float16* __restrict__ Al,
    const _Float16* __restrict__ Bh, const _Float16* __restrict__ Bl,
    const float* __restrict__ bias, float* __restrict__ Cf,
    _Float16* __restrict__ Oh, _Float16* __restrict__ Ol, int K, int Ndim,
    int relu, int kz) {
  __shared__ _Float16 lds[2 * 7680];  // per buf: Ah1280 Al1280 Bh2560 Bl2560
  const int t = threadIdx.x;
  const int m0 = blockIdx.x * 32, n0 = blockIdx.y * 32 * 2;
  const int kchunk = K / kz;
  const int kbase = blockIdx.z * kchunk;
  const int KT = kchunk >> 5;
  const int lane = t & 63, wave = t >> 6;
  const int tm = wave >> 1, tn0 = (wave & 1) * 2;
  const int quad = lane >> 4, l15 = lane & 15;
  // staging: A covered by i=0 (256 uint4), Bh by i=1, Bl by i=2
  const int arow = (t & 127) >> 2, aq = ((t & 127) & 3) * 8;
  const int brow = t >> 2, bq = (t & 3) * 8;
  const _Float16* srcA = ((t < 128) ? Ah : Al) + (size_t)(m0 + arow) * K;
  const _Float16* srcBh = Bh + (size_t)(n0 + brow) * K;
  const _Float16* srcBl = Bl + (size_t)(n0 + brow) * K;
  const int ldsA = (t < 128 ? 0 : 1280) + arow * 40 + aq;
  const int ldsBh = 2560 + brow * 40 + bq;
  const int ldsBl = 5120 + brow * 40 + bq;
  uint4 rg[3];
  auto load = [&](int kt) {
    const int ka = kbase + kt * 32;
    rg[0] = *(const uint4*)&srcA[ka + aq];
    rg[1] = *(const uint4*)&srcBh[ka + bq];
    rg[2] = *(const uint4*)&srcBl[ka + bq];
  };
  auto store = [&](int buf) {
    const int b = buf * 7680;
    *(uint4*)&lds[b + ldsA] = rg[0];
    *(uint4*)&lds[b + ldsBh] = rg[1];
    *(uint4*)&lds[b + ldsBl] = rg[2];
  };
  floatx4 hh[2] = {{0.f, 0.f, 0.f, 0.f}, {0.f, 0.f, 0.f, 0.f}};
  floatx4 mid[2] = {{0.f, 0.f, 0.f, 0.f}, {0.f, 0.f, 0.f, 0.f}};
  load(0);
  store(0);
  const int ard = (tm * 16 + l15) * 40 + quad * 8;
  for (int kt = 0; kt < KT; kt++) {
    __syncthreads();
    if (kt + 1 < KT) load(kt + 1);
    const int b = (kt & 1) * 7680;
    half8 a_h = *(const half8*)&lds[b + ard];
    half8 a_l = *(const half8*)&lds[b + 1280 + ard];
#pragma unroll
    for (int j = 0; j < 2; j++) {
      const int brd = ((tn0 + j) * 16 + l15) * 40 + quad * 8;
      half8 b_h = *(const half8*)&lds[b + 2560 + brd];
      half8 b_l = *(const half8*)&lds[b + 5120 + brd];
      hh[j] = __builtin_amdgcn_mfma_f32_16x16x32_f16(a_h, b_h, hh[j], 0, 0, 0);
      mid[j] =
          __builtin_amdgcn_mfma_f32_16x16x32_f16(a_h, b_l, mid[j], 0, 0, 0);
      mid[j] =
          __builtin_amdgcn_mfma_f32_16x16x32_f16(a_l, b_h, mid[j], 0, 0, 0);
    }
    if (kt + 1 < KT) {
      __syncthreads();
      store((kt + 1) & 1);
    }
  }
#pragma unroll
  for (int j = 0; j < 2; j++)
#pragma unroll
    for (int r = 0; r < 4; r++) {
      float v = hh[j][r] + mid[j][r] * (1.0f / 2048.0f);
      int m = m0 + tm * 16 + quad * 4 + r;
      int n = n0 + (tn0 + j) * 16 + l15;
      if (kz == 1) {
        v += bias[n];
        if (relu) v = fmaxf(v, 0.0f);
        if (Cf) Cf[(size_t)m * Ndim + n] = v;
        if (Oh) {
          _Float16 h, l;
          split16(v, h, l);
          Oh[(size_t)m * Ndim + n] = h;
          Ol[(size_t)m * Ndim + n] = l;
        }
      } else {
        if (blockIdx.z == 0) v += bias[n];
        atomicAdd(&Cf[(size_t)m * Ndim + n], v);
      }
    }
}

// ---------------- kv projection: 64 batched [512x64x512], 64x64 tile -------
__global__ __launch_bounds__(256) void kv_mfma(
    const _Float16* __restrict__ Fh, const _Float16* __restrict__ Fl,
    const _Float16* __restrict__ Wkh, const _Float16* __restrict__ Wkl,
    const _Float16* __restrict__ Wvh, const _Float16* __restrict__ Wvl,
    const float* __restrict__ bk, const float* __restrict__ bv,
    float* __restrict__ keys, float* __restrict__ vals) {
  __shared__ _Float16 lds[2 * 10240];  // per buf: 4 arrays x 64x40
  const int t = threadIdx.x;
  const int m0 = blockIdx.x * 64;
  const int lh = blockIdx.y;  // l*8 + h
  const int is_v = blockIdx.z;
  const _Float16* pBh = (is_v ? Wvh : Wkh) + (size_t)lh * D * E;
  const _Float16* pBl = (is_v ? Wvl : Wkl) + (size_t)lh * D * E;
  const float* bb = (is_v ? bv : bk) + lh * D;
  float* outp = is_v ? vals : keys;
  const int l = lh >> 3, h = lh & 7;
  const int lane = t & 63, wave = t >> 6;
  const int wm = wave >> 1, wn = wave & 1;
  const int quad = lane >> 4, l15 = lane & 15;
  const int srow = t >> 2, sq = (t & 3) * 8;
  const _Float16* gsrc[4] = {Fh + (size_t)(m0 + srow) * E,
                             Fl + (size_t)(m0 + srow) * E,
                             pBh + (size_t)srow * E, pBl + (size_t)srow * E};
  const int lbase = srow * 40 + sq;
  uint4 rg[4];
  auto load = [&](int kt) {
    const int ka = kt * 32 + sq;
#pragma unroll
    for (int i = 0; i < 4; i++) rg[i] = *(const uint4*)&gsrc[i][kt * 32 + sq - sq + ka - kt * 32 + kt * 32];  // = gsrc[i][ka]
  };
  auto loadx = [&](int kt) {
    const int ka = kt * 32 + sq;
#pragma unroll
    for (int i = 0; i < 4; i++) rg[i] = *(const uint4*)&gsrc[i][ka];
  };
  (void)load;
  auto store = [&](int buf) {
#pragma unroll
    for (int i = 0; i < 4; i++)
      *(uint4*)&lds[buf * 10240 + i * 2560 + lbase] = rg[i];
  };
  floatx4 hh[2][2], mid[2][2];
#pragma unroll
  for (int i = 0; i < 2; i++)
#pragma unroll
    for (int j = 0; j < 2; j++) {
      hh[i][j] = (floatx4){0.f, 0.f, 0.f, 0.f};
      mid[i][j] = (floatx4){0.f, 0.f, 0.f, 0.f};
    }
  loadx(0);
  store(0);
  constexpr int KT = E / 32;  // 16
  for (int kt = 0; kt < KT; kt++) {
    __syncthreads();
    if (kt + 1 < KT) loadx(kt + 1);
    const int b = (kt & 1) * 10240;
    half8 a_h[2], a_l[2], b_h[2], b_l[2];
#pragma unroll
    for (int i = 0; i < 2; i++) {
      const int ar = (wm * 32 + i * 16 + l15) * 40 + quad * 8;
      const int br = (wn * 32 + i * 16 + l15) * 40 + quad * 8;
      a_h[i] = *(const half8*)&lds[b + ar];
      a_l[i] = *(const half8*)&lds[b + 2560 + ar];
      b_h[i] = *(const half8*)&lds[b + 5120 + br];
      b_l[i] = *(const half8*)&lds[b + 7680 + br];
    }
#pragma unroll
    for (int i = 0; i < 2; i++)
#pragma unroll
      for (int j = 0; j < 2; j++) {
        hh[i][j] = __builtin_amdgcn_mfma_f32_16x16x32_f16(a_h[i], b_h[j],
                                                          hh[i][j], 0, 0, 0);
        mid[i][j] = __builtin_amdgcn_mfma_f32_16x16x32_f16(a_h[i], b_l[j],
                                                           mid[i][j], 0, 0, 0);
        mid[i][j] = __builtin_amdgcn_mfma_f32_16x16x32_f16(a_l[i], b_h[j],
                                                           mid[i][j], 0, 0, 0);
      }
    if (kt + 1 < KT) {
      __syncthreads();
      store((kt + 1) & 1);
    }
  }
#pragma unroll
  for (int i = 0; i < 2; i++)
#pragma unroll
    for (int j = 0; j < 2; j++)
#pragma unroll
      for (int r = 0; r < 4; r++) {
        float v = hh[i][j][r] + mid[i][j][r] * (1.0f / 2048.0f);
        int m = m0 + wm * 32 + i * 16 + quad * 4 + r;  // row = b*64 + v
        int n = wn * 32 + j * 16 + l15;                // d
        v += bb[n];
        int b_ = m >> 6, v_ = m & 63;
        outp[(((size_t)(l * B + b_) * H + h) * V + v_) * D + n] = v;
      }
}

// ---------------- fused attention + residual + LN1 (one block per row) -----
__global__ __launch_bounds__(256) void attn_kernel(
    float* __restrict__ att, _Float16* __restrict__ att_h,
    _Float16* __restrict__ att_l, const float* __restrict__ keys,
    const float* __restrict__ vals, const float* __restrict__ g,
    const float* __restrict__ bb, int l) {
  __shared__ float q[HD];
  __shared__ float sp[HD];
  __shared__ double rb[8];
  const int t = threadIdx.x;
  const int row = blockIdx.x;
  const int b_ = row >> 6;
  q[t]       = att[row * HD + t];
  q[t + 256] = att[row * HD + 256 + t];
  __syncthreads();
#pragma unroll
  for (int rep = 0; rep < 2; rep++) {
    int idx = t + rep * 256;
    int h = idx >> 6, w = idx & 63;
    const float* kp = keys + (((size_t)(l * B + b_) * H + h) * V + w) * D;
    const float* qp = q + h * D;
    double s = 0.0;
#pragma unroll 8
    for (int d = 0; d < 64; d++) s += (double)qp[d] * (double)kp[d];
    sp[idx] = (float)s * 0.125f;
  }
  __syncthreads();
  {
    int h = t >> 5, w0 = t & 31;
    float s0 = sp[h * 64 + w0], s1 = sp[h * 64 + w0 + 32];
    float mx = fmaxf(s0, s1);
#pragma unroll
    for (int m = 16; m; m >>= 1) mx = fmaxf(mx, __shfl_xor(mx, m, 32));
    float e0 = expf(s0 - mx), e1 = expf(s1 - mx);
    double sm = (double)e0 + (double)e1;
#pragma unroll
    for (int m = 16; m; m >>= 1) sm += __shfl_xor(sm, m, 32);
    sp[h * 64 + w0]      = (float)((double)e0 / sm);
    sp[h * 64 + w0 + 32] = (float)((double)e1 / sm);
  }
  __syncthreads();
  float x[2];
#pragma unroll
  for (int rep = 0; rep < 2; rep++) {
    int idx = t + rep * 256;
    int h = idx >> 6, d = idx & 63;
    const float* vp = vals + (((size_t)(l * B + b_) * H + h) * V) * D + d;
    const float* pp = sp + h * 64;
    double a = 0.0;
#pragma unroll 8
    for (int w = 0; w < 64; w++) a += (double)pp[w] * (double)vp[w * 64];
    x[rep] = q[idx] + (float)a;
  }
  double s1 = (double)x[0] + (double)x[1];
  double s2 = (double)x[0] * (double)x[0] + (double)x[1] * (double)x[1];
  s1 = waveReduceAdd64(s1);
  s2 = waveReduceAdd64(s2);
  const int wid = t >> 6, lane = t & 63;
  if (lane == 0) { rb[wid] = s1; rb[4 + wid] = s2; }
  __syncthreads();
  double S1 = rb[0] + rb[1] + rb[2] + rb[3];
  double S2 = rb[4] + rb[5] + rb[6] + rb[7];
  double mean = S1 / (double)HD;
  double var  = S2 / (double)HD - mean * mean;
  double inv  = 1.0 / sqrt(var + (double)1e-5f);
  float y0 =
      (float)(((double)x[0] - mean) * inv * (double)g[t] + (double)bb[t]);
  float y1 = (float)(((double)x[1] - mean) * inv * (double)g[t + 256] +
                     (double)bb[t + 256]);
  att[row * HD + t] = y0;
  att[row * HD + 256 + t] = y1;
  _Float16 h0, l0, h1v, l1v;
  split16(y0, h0, l0);
  split16(y1, h1v, l1v);
  att_h[row * HD + t] = h0;
  att_l[row * HD + t] = l0;
  att_h[row * HD + 256 + t] = h1v;
  att_l[row * HD + 256 + t] = l1v;
}

// ---------------- residual + LN2 (consumes f32 h3, re-zeros it) ------------
__global__ __launch_bounds__(256) void ln_res_kernel(
    float* __restrict__ att, _Float16* __restrict__ att_h,
    _Float16* __restrict__ att_l, float* __restrict__ h3,
    const float* __restrict__ g, const float* __restrict__ bb) {
  __shared__ double rb[8];
  const int t = threadIdx.x;
  const int row = blockIdx.x;
  float x0 = att[row * HD + t] + h3[row * HD + t];
  float x1 = att[row * HD + 256 + t] + h3[row * HD + 256 + t];
  h3[row * HD + t] = 0.0f;
  h3[row * HD + 256 + t] = 0.0f;
  double s1 = (double)x0 + (double)x1;
  double s2 = (double)x0 * (double)x0 + (double)x1 * (double)x1;
  s1 = waveReduceAdd64(s1);
  s2 = waveReduceAdd64(s2);
  const int wid = t >> 6, lane = t & 63;
  if (lane == 0) { rb[wid] = s1; rb[4 + wid] = s2; }
  __syncthreads();
  double S1 = rb[0] + rb[1] + rb[2] + rb[3];
  double S2 = rb[4] + rb[5] + rb[6] + rb[7];
  double mean = S1 / (double)HD;
  double var  = S2 / (double)HD - mean * mean;
  double inv  = 1.0 / sqrt(var + (double)1e-5f);
  float y0 = (float)(((double)x0 - mean) * inv * (double)g[t] + (double)bb[t]);
  float y1 = (float)(((double)x1 - mean) * inv * (double)g[t + 256] +
                     (double)bb[t + 256]);
  att[row * HD + t] = y0;
  att[row * HD + 256 + t] = y1;
  _Float16 h0, l0, h1v, l1v;
  split16(y0, h0, l0);
  split16(y1, h1v, l1v);
  att_h[row * HD + t] = h0;
  att_l[row * HD + t] = l0;
  att_h[row * HD + 256 + t] = h1v;
  att_l[row * HD + 256 + t] = l1v;
}

// ---------------- gumbel-argmax sampling (bit-exact vs JAX; verified) ------
__global__ __launch_bounds__(256) void sample_kernel(
    const float* __restrict__ logits, float* __restrict__ out) {
  constexpr TF2 KC = threefry(0u, 1u, 0u, 0u);  // fold_in(key(1), 0)
  constexpr TF2 KU = threefry(0u, 1u, 0u, 1u);  // fold_in(key(1), 1)
  const int lane = threadIdx.x & 63;
  const int wid = threadIdx.x >> 6;
  const int row = blockIdx.x * 4 + wid;
  const float* lrow = logits + (row >> 5) * R;
  float bvv = -1e30f;
  int bi = 0;
#pragma unroll
  for (int rep = 0; rep < 2; rep++) {
    int r = lane + rep * 64;
    unsigned j = (unsigned)row * (unsigned)R + (unsigned)r;
    unsigned bits = tf_bits32(KC.a, KC.b, j);
    float f = __uint_as_float((bits >> 9) | 0x3f800000u) - 1.0f;
    float u = fmaxf(f, 1.17549435e-38f);
    float gv = -logf(-logf(u));
    float v = lrow[r] + gv;
    if (v > bvv) { bvv = v; bi = r; }
  }
#pragma unroll
  for (int m = 32; m; m >>= 1) {
    float ov = __shfl_xor(bvv, m, 64);
    int oi = __shfl_xor(bi, m, 64);
    if (ov > bvv || (ov == bvv && oi < bi)) { bvv = ov; bi = oi; }
  }
  if (lane == 0) {
    unsigned ub = tf_bits32(KU.a, KU.b, (unsigned)row);
    float u = __uint_as_float((ub >> 9) | 0x3f800000u) - 1.0f;
    out[row] = ((float)bi + u) * (1.0f / 128.0f);
  }
}

// ---------------- launcher ----------------
extern "C" void kernel_launch(void* const* d_in, const int* in_sizes, int n_in,
                              void* d_out, int out_size, void* d_ws,
                              size_t ws_size, hipStream_t stream) {
  (void)in_sizes; (void)n_in; (void)out_size; (void)ws_size;
  const float* flow = (const float*)d_in[0];
  const float* Wsh  = (const float*)d_in[1];
  const float* bsh  = (const float*)d_in[2];
  const float* Wk   = (const float*)d_in[3];
  const float* bk   = (const float*)d_in[4];
  const float* Wv   = (const float*)d_in[5];
  const float* bv   = (const float*)d_in[6];
  const float* ln1g = (const float*)d_in[7];
  const float* ln1b = (const float*)d_in[8];
  const float* W1   = (const float*)d_in[9];
  const float* b1   = (const float*)d_in[10];
  const float* W2   = (const float*)d_in[11];
  const float* b2   = (const float*)d_in[12];
  const float* W3   = (const float*)d_in[13];
  const float* b3   = (const float*)d_in[14];
  const float* ln2g = (const float*)d_in[15];
  const float* ln2b = (const float*)d_in[16];
  const float* Wd   = (const float*)d_in[17];
  const float* bd   = (const float*)d_in[18];

  // ---- workspace carve-up (f32 region then fp16 region; 16B aligned) ------
  float* ws = (float*)d_ws;
  float* keys   = ws;                         // 1,048,576 f32
  float* vals   = keys + 1048576;             // 1,048,576
  float* att    = vals + 1048576;             // 262,144   (zeroed)
  float* h3     = att + 262144;               // 262,144   (zeroed)
  float* logits = h3 + 262144;                // 65,536    (zeroed)
  _Float16* hp = (_Float16*)(logits + 65536);
  _Float16* flow_h = hp;            hp += 262144;
  _Float16* flow_l = hp;            hp += 262144;
  _Float16* Wsh_h  = hp;            hp += 262144;
  _Float16* Wsh_l  = hp;            hp += 262144;
  _Float16* Wk_h   = hp;            hp += 1048576;
  _Float16* Wk_l   = hp;            hp += 1048576;
  _Float16* Wv_h   = hp;            hp += 1048576;
  _Float16* Wv_l   = hp;            hp += 1048576;
  _Float16* W1_h   = hp;            hp += 2097152;
  _Float16* W1_l   = hp;            hp += 2097152;
  _Float16* W2_h   = hp;            hp += 4194304;
  _Float16* W2_l   = hp;            hp += 4194304;
  _Float16* W3_h   = hp;            hp += 2097152;
  _Float16* W3_l   = hp;            hp += 2097152;
  _Float16* Wd_h   = hp;            hp += 65536;
  _Float16* Wd_l   = hp;            hp += 65536;
  _Float16* att_h  = hp;            hp += 262144;
  _Float16* att_l  = hp;            hp += 262144;
  _Float16* h1_h   = hp;            hp += 524288;
  _Float16* h1_l   = hp;            hp += 524288;
  _Float16* h2_h   = hp;            hp += 524288;
  _Float16* h2_l   = hp;            hp += 524288;   // ~60 MB total

  // ---- zero accumulation targets (att, h3, logits contiguous) ----
  zero_kernel<<<576, 256, 0, stream>>>(att);

  // ---- input splitting (2 launches) ----
  asplit<<<256, 256, 0, stream>>>(flow, flow_h, flow_l);
  WArgs wa;
  wa.s[0] = Wsh; wa.h[0] = Wsh_h; wa.l[0] = Wsh_l;
  wa.s[1] = Wk;  wa.h[1] = Wk_h;  wa.l[1] = Wk_l;
  wa.s[2] = Wv;  wa.h[2] = Wv_h;  wa.l[2] = Wv_l;
  wa.s[3] = W1;  wa.h[3] = W1_h;  wa.l[3] = W1_l;
  wa.s[4] = W2;  wa.h[4] = W2_h;  wa.l[4] = W2_l;
  wa.s[5] = W3;  wa.h[5] = W3_h;  wa.l[5] = W3_l;
  wa.s[6] = Wd;  wa.h[6] = Wd_h;  wa.l[6] = Wd_l;
  wsplit_all<<<2640, 256, 0, stream>>>(wa);

  // ---- keys/vals + shift ----
  kv_mfma<<<dim3(8, 32, 2), 256, 0, stream>>>(flow_h, flow_l, Wk_h, Wk_l,
                                              Wv_h, Wv_l, bk, bv, keys, vals);
  mfma_gemm<<<dim3(16, 8, 2), 256, 0, stream>>>(
      flow_h, flow_l, Wsh_h, Wsh_l, bsh, att, nullptr, nullptr, 512, 512, 0,
      2);
  // ---- transformer layers ----
  for (int l = 0; l < L; l++) {
    attn_kernel<<<ROWS, 256, 0, stream>>>(att, att_h, att_l, keys, vals,
                                          ln1g + l * HD, ln1b + l * HD, l);
    mfma_gemm<<<dim3(16, 16, 1), 256, 0, stream>>>(
        att_h, att_l, W1_h + (size_t)l * 524288, W1_l + (size_t)l * 524288,
        b1 + l * M, nullptr, h1_h, h1_l, 512, 1024, 1, 1);
    mfma_gemm<<<dim3(16, 16, 1), 256, 0, stream>>>(
        h1_h, h1_l, W2_h + (size_t)l * 1048576, W2_l + (size_t)l * 1048576,
        b2 + l * M, nullptr, h2_h, h2_l, 1024, 1024, 1, 1);
    mfma_gemm<<<dim3(16, 8, 2), 256, 0, stream>>>(
        h2_h, h2_l, W3_h + (size_t)l * 524288, W3_l + (size_t)l * 524288,
        b3 + l * HD, h3, nullptr, nullptr, 1024, 512, 0, 2);
    ln_res_kernel<<<ROWS, 256, 0, stream>>>(att, att_h, att_l, h3,
                                            ln2g + l * HD, ln2b + l * HD);
  }
  // ---- distribution head + sampling ----
  mfma_gemm<<<dim3(16, 2, 4), 256, 0, stream>>>(att_h, att_l, Wd_h, Wd_l, bd,
                                                logits, nullptr, nullptr, 512,
                                                128, 0, 4);
  sample_kernel<<<SROWS / 4, 256, 0, stream>>>(logits, (float*)d_out);
}

// Round 6
// 527.966 us; speedup vs baseline: 3.7677x; 1.1342x over previous
//
#include <hip/hip_runtime.h>
#include <hip/hip_bf16.h>
#include <math.h>

// ---------------- problem dims (fixed by setup_inputs) ----------------
constexpr int B  = 8,  V = 64, E = 512, NS = 32;
constexpr int L  = 4,  H = 8,  D = 64,  M  = 1024, R = 128;
constexpr int HD = H * D;            // 512
constexpr int ROWS  = B * V;         // 512 distinct transformer rows
constexpr int SROWS = ROWS * NS;     // 16384 sample rows
constexpr int KVN = 4096;            // kv output columns (keys 2048 | vals 2048)

typedef _Float16 half8 __attribute__((ext_vector_type(8)));
typedef float floatx4 __attribute__((ext_vector_type(4)));

// ---------------- threefry2x32-20 (JAX-compatible, partitionable) ----------
struct TF2 { unsigned a, b; };
__host__ __device__ constexpr unsigned rotl32(unsigned x, int d) {
  return (x << d) | (x >> (32 - d));
}
__host__ __device__ constexpr TF2 threefry(unsigned k0, unsigned k1,
                                           unsigned x0, unsigned x1) {
  unsigned ks2 = k0 ^ k1 ^ 0x1BD11BDAu;
  x0 += k0; x1 += k1;
  const int ra[4] = {13, 15, 26, 6};
  const int rb[4] = {17, 29, 16, 24};
  for (int i = 0; i < 4; i++) { x0 += x1; x1 = rotl32(x1, ra[i]); x1 ^= x0; }
  x0 += k1;  x1 += ks2 + 1u;
  for (int i = 0; i < 4; i++) { x0 += x1; x1 = rotl32(x1, rb[i]); x1 ^= x0; }
  x0 += ks2; x1 += k0 + 2u;
  for (int i = 0; i < 4; i++) { x0 += x1; x1 = rotl32(x1, ra[i]); x1 ^= x0; }
  x0 += k0;  x1 += k1 + 3u;
  for (int i = 0; i < 4; i++) { x0 += x1; x1 = rotl32(x1, rb[i]); x1 ^= x0; }
  x0 += k1;  x1 += ks2 + 4u;
  for (int i = 0; i < 4; i++) { x0 += x1; x1 = rotl32(x1, ra[i]); x1 ^= x0; }
  x0 += ks2; x1 += k0 + 5u;
  return {x0, x1};
}
__device__ __forceinline__ unsigned tf_bits32(unsigned k0, unsigned k1,
                                              unsigned j) {
  TF2 r = threefry(k0, k1, 0u, j);
  return r.a ^ r.b;
}

__device__ __forceinline__ double waveReduceAdd64(double v) {
#pragma unroll
  for (int m = 32; m; m >>= 1) v += __shfl_xor(v, m, 64);
  return v;
}

__device__ __forceinline__ void split16(float v, _Float16& h, _Float16& l) {
  h = (_Float16)v;
  l = (_Float16)((v - (float)h) * 2048.0f);
}

// ---------------- prep: flow split + h3 zero + kv/shift bias vector --------
__global__ __launch_bounds__(256) void prep_kernel(
    const float* __restrict__ flow, const float* __restrict__ bk,
    const float* __restrict__ bv, const float* __restrict__ bsh,
    _Float16* __restrict__ fh, _Float16* __restrict__ fl,
    float* __restrict__ h3, float* __restrict__ kvb) {
  const int blk = blockIdx.x, t = threadIdx.x;
  if (blk < 256) {
    const int base = (blk * 256 + t) * 4;
    float4 v = *(const float4*)&flow[base];
    float a[4] = {v.x, v.y, v.z, v.w};
#pragma unroll
    for (int j = 0; j < 4; j++) {
      _Float16 h, l;
      split16(a[j], h, l);
      fh[base + j] = h;
      fl[base + j] = l;
    }
  } else {
    const int idx = (blk - 256) * 256 + t;
    float4 z = {0.f, 0.f, 0.f, 0.f};
    *(float4*)&h3[idx * 4] = z;
    if (idx < KVN + HD) {
      float bb = (idx < 2048) ? bk[idx]
               : (idx < 4096) ? bv[idx - 2048]
                              : bsh[idx - 4096];
      kvb[idx] = bb;
    }
  }
}

// ---------------- all-weights transpose + split in ONE launch --------------
struct WArgs {
  const float* s[7];
  _Float16* h[7];
  _Float16* l[7];
};
// 0 Wsh(512,512) 1 Wk(512,64)x32 2 Wv(512,64)x32 3 W1(512,1024)x4
// 4 W2(1024,1024)x4 5 W3(1024,512)x4 6 Wd(512,128)
__global__ __launch_bounds__(256) void wsplit_all(WArgs a) {
  const int WS_OFF[8] = {0, 64, 320, 576, 1088, 2112, 2624, 2640};
  const int WS_K[7] = {512, 512, 512, 512, 1024, 1024, 512};
  const int WS_N[7] = {512, 64, 64, 1024, 1024, 512, 128};
  __shared__ float tile[64][65];
  int bid = blockIdx.x;
  int mi = 0;
  while (bid >= WS_OFF[mi + 1]) mi++;
  int tt = bid - WS_OFF[mi];
  const int K = WS_K[mi], N = WS_N[mi];
  const int ktiles = K >> 6;
  const int per = ktiles * (N >> 6);
  const int z = tt / per;
  const int rem = tt - z * per;
  const int k0 = (rem % ktiles) * 64, n0 = (rem / ktiles) * 64;
  const size_t moff = (size_t)z * K * N;
  const float* src = a.s[mi] + moff;
  _Float16* dh = a.h[mi] + moff;
  _Float16* dl = a.l[mi] + moff;
  const int t = threadIdx.x;
#pragma unroll
  for (int i = 0; i < 16; i++) {
    int idx = i * 256 + t, r = idx >> 6, c = idx & 63;
    tile[r][c] = src[(size_t)(k0 + r) * N + n0 + c];
  }
  __syncthreads();
#pragma unroll
  for (int i = 0; i < 16; i++) {
    int idx = i * 256 + t, n = idx >> 6, k = idx & 63;
    float v = tile[k][n];
    _Float16 h, l;
    split16(v, h, l);
    dh[(size_t)(n0 + n) * K + k0 + k] = h;
    dl[(size_t)(n0 + n) * K + k0 + k] = l;
  }
}

// ---------------- 64x64 MFMA GEMM, async LDS staging, fragment-order -------
// A_h/A_l: [M][K] fp16. B_h/B_l: [N][K] fp16. BK=32, double-buffered.
// Fragment-order LDS: each 16x32 fragment = 64 lanes x 16B, lane-major --
// matches global_load_lds's fixed dest (base + lane*16) AND bank-balanced
// ds_read_b128. Wave w stages frag w of each array; computes 2x2 frags
// (wm=w>>1, wn=w&1). Per K-step/wave: 4 gll + 8 ds_read_b128 + 12 MFMA.
// kz==1: epilogue bias(+relu), route n<nsplit -> C0 else C1; opt h/l split.
// kz>1 : f32 atomicAdd into pre-zeroed C0 (deterministic for kz=2).
__global__ __launch_bounds__(256) void mfma_gemm(
    const _Float16* __restrict__ Ah, const _Float16* __restrict__ Al,
    const _Float16* __restrict__ Bh, const _Float16* __restrict__ Bl,
    const float* __restrict__ bias, float* __restrict__ C0, int ldc0,
    float* __restrict__ C1, int ldc1, int nsplit,
    _Float16* __restrict__ Oh, _Float16* __restrict__ Ol, int K, int relu,
    int kz) {
  __shared__ __align__(16) _Float16 lds[2 * 8192];
  const int t = threadIdx.x;
  const int lane = t & 63, wave = t >> 6;
  const int quad = lane >> 4, l15 = lane & 15;
  const int m0 = blockIdx.x * 64, n0 = blockIdx.y * 64;
  const int kchunk = K / kz, kbase = blockIdx.z * kchunk;
  const int KT = kchunk >> 5;
  // per-lane global sources for this wave's staged fragment (frag index = wave)
  const _Float16* gAh = Ah + (size_t)(m0 + wave * 16 + l15) * K + quad * 8 + kbase;
  const _Float16* gAl = Al + (size_t)(m0 + wave * 16 + l15) * K + quad * 8 + kbase;
  const _Float16* gBh = Bh + (size_t)(n0 + wave * 16 + l15) * K + quad * 8 + kbase;
  const _Float16* gBl = Bl + (size_t)(n0 + wave * 16 + l15) * K + quad * 8 + kbase;
  auto stage = [&](int buf, int kt) {
    const int koff = kt * 32;
    _Float16* base = &lds[buf * 8192 + wave * 512];
    __builtin_amdgcn_global_load_lds(gAh + koff, base, 16, 0, 0);
    __builtin_amdgcn_global_load_lds(gAl + koff, base + 2048, 16, 0, 0);
    __builtin_amdgcn_global_load_lds(gBh + koff, base + 4096, 16, 0, 0);
    __builtin_amdgcn_global_load_lds(gBl + koff, base + 6144, 16, 0, 0);
  };
  const int wm = wave >> 1, wn = wave & 1;
  floatx4 hh[2][2], mid[2][2];
#pragma unroll
  for (int i = 0; i < 2; i++)
#pragma unroll
    for (int j = 0; j < 2; j++) {
      hh[i][j] = (floatx4){0.f, 0.f, 0.f, 0.f};
      mid[i][j] = (floatx4){0.f, 0.f, 0.f, 0.f};
    }
  stage(0, 0);
  __syncthreads();
  for (int kt = 0; kt < KT; kt++) {
    if (kt + 1 < KT) stage((kt + 1) & 1, kt + 1);
    const int b = (kt & 1) * 8192;
    half8 a_h[2], a_l[2], b_h[2], b_l[2];
#pragma unroll
    for (int i = 0; i < 2; i++) {
      const int af = (wm * 2 + i) * 512 + lane * 8;
      const int bf = (wn * 2 + i) * 512 + lane * 8;
      a_h[i] = *(const half8*)&lds[b + af];
      a_l[i] = *(const half8*)&lds[b + 2048 + af];
      b_h[i] = *(const half8*)&lds[b + 4096 + bf];
      b_l[i] = *(const half8*)&lds[b + 6144 + bf];
    }
#pragma unroll
    for (int i = 0; i < 2; i++)
#pragma unroll
      for (int j = 0; j < 2; j++) {
        hh[i][j] = __builtin_amdgcn_mfma_f32_16x16x32_f16(a_h[i], b_h[j],
                                                          hh[i][j], 0, 0, 0);
        mid[i][j] = __builtin_amdgcn_mfma_f32_16x16x32_f16(a_h[i], b_l[j],
                                                           mid[i][j], 0, 0, 0);
        mid[i][j] = __builtin_amdgcn_mfma_f32_16x16x32_f16(a_l[i], b_h[j],
                                                           mid[i][j], 0, 0, 0);
      }
    __syncthreads();
  }
#pragma unroll
  for (int i = 0; i < 2; i++)
#pragma unroll
    for (int j = 0; j < 2; j++)
#pragma unroll
      for (int r = 0; r < 4; r++) {
        float v = hh[i][j][r] + mid[i][j][r] * (1.0f / 2048.0f);
        const int m = m0 + (wm * 2 + i) * 16 + quad * 4 + r;
        const int n = n0 + (wn * 2 + j) * 16 + l15;
        if (kz == 1) {
          v += bias[n];
          if (relu) v = fmaxf(v, 0.0f);
          if (n < nsplit) {
            if (C0) C0[(size_t)m * ldc0 + n] = v;
            if (Oh) {
              _Float16 h, l;
              split16(v, h, l);
              Oh[(size_t)m * ldc0 + n] = h;
              Ol[(size_t)m * ldc0 + n] = l;
            }
          } else {
            C1[(size_t)m * ldc1 + (n - nsplit)] = v;
          }
        } else {
          if (blockIdx.z == 0) v += bias[n];
          atomicAdd(&C0[(size_t)m * ldc0 + n], v);
        }
      }
}

// ---------------- fused attention + residual + LN1 (one block per row) -----
// kv layout: kv[m=b*64+var][n], keys at n=(l*8+h)*64+d, vals at n+2048.
__global__ __launch_bounds__(256) void attn_kernel(
    float* __restrict__ att, _Float16* __restrict__ att_h,
    _Float16* __restrict__ att_l, const float* __restrict__ kv,
    const float* __restrict__ g, const float* __restrict__ bb, int l) {
  __shared__ float q[HD];
  __shared__ float sp[HD];
  __shared__ double rb[8];
  const int t = threadIdx.x;
  const int row = blockIdx.x;
  const int b_ = row >> 6;
  q[t]       = att[row * HD + t];
  q[t + 256] = att[row * HD + 256 + t];
  __syncthreads();
#pragma unroll
  for (int rep = 0; rep < 2; rep++) {
    int idx = t + rep * 256;
    int h = idx >> 6, w = idx & 63;
    const float* kp = kv + (size_t)(b_ * 64 + w) * KVN + (l * 8 + h) * 64;
    const float* qp = q + h * D;
    double s = 0.0;
#pragma unroll 8
    for (int d = 0; d < 64; d++) s += (double)qp[d] * (double)kp[d];
    sp[idx] = (float)s * 0.125f;
  }
  __syncthreads();
  {
    int h = t >> 5, w0 = t & 31;
    float s0 = sp[h * 64 + w0], s1 = sp[h * 64 + w0 + 32];
    float mx = fmaxf(s0, s1);
#pragma unroll
    for (int m = 16; m; m >>= 1) mx = fmaxf(mx, __shfl_xor(mx, m, 32));
    float e0 = expf(s0 - mx), e1 = expf(s1 - mx);
    double sm = (double)e0 + (double)e1;
#pragma unroll
    for (int m = 16; m; m >>= 1) sm += __shfl_xor(sm, m, 32);
    sp[h * 64 + w0]      = (float)((double)e0 / sm);
    sp[h * 64 + w0 + 32] = (float)((double)e1 / sm);
  }
  __syncthreads();
  float x[2];
#pragma unroll
  for (int rep = 0; rep < 2; rep++) {
    int idx = t + rep * 256;
    int h = idx >> 6, d = idx & 63;
    const float* vp = kv + (size_t)(b_ * 64) * KVN + 2048 + (l * 8 + h) * 64 + d;
    const float* pp = sp + h * 64;
    double a = 0.0;
#pragma unroll 8
    for (int w = 0; w < 64; w++) a += (double)pp[w] * (double)vp[(size_t)w * KVN];
    x[rep] = q[idx] + (float)a;
  }
  double s1 = (double)x[0] + (double)x[1];
  double s2 = (double)x[0] * (double)x[0] + (double)x[1] * (double)x[1];
  s1 = waveReduceAdd64(s1);
  s2 = waveReduceAdd64(s2);
  const int wid = t >> 6, lane = t & 63;
  if (lane == 0) { rb[wid] = s1; rb[4 + wid] = s2; }
  __syncthreads();
  double S1 = rb[0] + rb[1] + rb[2] + rb[3];
  double S2 = rb[4] + rb[5] + rb[6] + rb[7];
  double mean = S1 / (double)HD;
  double var  = S2 / (double)HD - mean * mean;
  double inv  = 1.0 / sqrt(var + (double)1e-5f);
  float y0 =
      (float)(((double)x[0] - mean) * inv * (double)g[t] + (double)bb[t]);
  float y1 = (float)(((double)x[1] - mean) * inv * (double)g[t + 256] +
                     (double)bb[t + 256]);
  att[row * HD + t] = y0;
  att[row * HD + 256 + t] = y1;
  _Float16 h0, l0, h1v, l1v;
  split16(y0, h0, l0);
  split16(y1, h1v, l1v);
  att_h[row * HD + t] = h0;
  att_l[row * HD + t] = l0;
  att_h[row * HD + 256 + t] = h1v;
  att_l[row * HD + 256 + t] = l1v;
}

// ---------------- residual + LN2 (consumes f32 h3, re-zeros it) ------------
__global__ __launch_bounds__(256) void ln_res_kernel(
    float* __restrict__ att, _Float16* __restrict__ att_h,
    _Float16* __restrict__ att_l, float* __restrict__ h3,
    const float* __restrict__ g, const float* __restrict__ bb) {
  __shared__ double rb[8];
  const int t = threadIdx.x;
  const int row = blockIdx.x;
  float x0 = att[row * HD + t] + h3[row * HD + t];
  float x1 = att[row * HD + 256 + t] + h3[row * HD + 256 + t];
  h3[row * HD + t] = 0.0f;
  h3[row * HD + 256 + t] = 0.0f;
  double s1 = (double)x0 + (double)x1;
  double s2 = (double)x0 * (double)x0 + (double)x1 * (double)x1;
  s1 = waveReduceAdd64(s1);
  s2 = waveReduceAdd64(s2);
  const int wid = t >> 6, lane = t & 63;
  if (lane == 0) { rb[wid] = s1; rb[4 + wid] = s2; }
  __syncthreads();
  double S1 = rb[0] + rb[1] + rb[2] + rb[3];
  double S2 = rb[4] + rb[5] + rb[6] + rb[7];
  double mean = S1 / (double)HD;
  double var  = S2 / (double)HD - mean * mean;
  double inv  = 1.0 / sqrt(var + (double)1e-5f);
  float y0 = (float)(((double)x0 - mean) * inv * (double)g[t] + (double)bb[t]);
  float y1 = (float)(((double)x1 - mean) * inv * (double)g[t + 256] +
                     (double)bb[t + 256]);
  att[row * HD + t] = y0;
  att[row * HD + 256 + t] = y1;
  _Float16 h0, l0, h1v, l1v;
  split16(y0, h0, l0);
  split16(y1, h1v, l1v);
  att_h[row * HD + t] = h0;
  att_l[row * HD + t] = l0;
  att_h[row * HD + 256 + t] = h1v;
  att_l[row * HD + 256 + t] = l1v;
}

// ---------------- gumbel-argmax sampling (bit-exact vs JAX; verified) ------
__global__ __launch_bounds__(256) void sample_kernel(
    const float* __restrict__ logits, float* __restrict__ out) {
  constexpr TF2 KC = threefry(0u, 1u, 0u, 0u);  // fold_in(key(1), 0)
  constexpr TF2 KU = threefry(0u, 1u, 0u, 1u);  // fold_in(key(1), 1)
  const int lane = threadIdx.x & 63;
  const int wid = threadIdx.x >> 6;
  const int row = blockIdx.x * 4 + wid;
  const float* lrow = logits + (row >> 5) * R;
  float bvv = -1e30f;
  int bi = 0;
#pragma unroll
  for (int rep = 0; rep < 2; rep++) {
    int r = lane + rep * 64;
    unsigned j = (unsigned)row * (unsigned)R + (unsigned)r;
    unsigned bits = tf_bits32(KC.a, KC.b, j);
    float f = __uint_as_float((bits >> 9) | 0x3f800000u) - 1.0f;
    float u = fmaxf(f, 1.17549435e-38f);
    float gv = -logf(-logf(u));
    float v = lrow[r] + gv;
    if (v > bvv) { bvv = v; bi = r; }
  }
#pragma unroll
  for (int m = 32; m; m >>= 1) {
    float ov = __shfl_xor(bvv, m, 64);
    int oi = __shfl_xor(bi, m, 64);
    if (ov > bvv || (ov == bvv && oi < bi)) { bvv = ov; bi = oi; }
  }
  if (lane == 0) {
    unsigned ub = tf_bits32(KU.a, KU.b, (unsigned)row);
    float u = __uint_as_float((ub >> 9) | 0x3f800000u) - 1.0f;
    out[row] = ((float)bi + u) * (1.0f / 128.0f);
  }
}

// ---------------- launcher ----------------
extern "C" void kernel_launch(void* const* d_in, const int* in_sizes, int n_in,
                              void* d_out, int out_size, void* d_ws,
                              size_t ws_size, hipStream_t stream) {
  (void)in_sizes; (void)n_in; (void)out_size; (void)ws_size;
  const float* flow = (const float*)d_in[0];
  const float* Wsh  = (const float*)d_in[1];
  const float* bsh  = (const float*)d_in[2];
  const float* Wk   = (const float*)d_in[3];
  const float* bk   = (const float*)d_in[4];
  const float* Wv   = (const float*)d_in[5];
  const float* bv   = (const float*)d_in[6];
  const float* ln1g = (const float*)d_in[7];
  const float* ln1b = (const float*)d_in[8];
  const float* W1   = (const float*)d_in[9];
  const float* b1   = (const float*)d_in[10];
  const float* W2   = (const float*)d_in[11];
  const float* b2   = (const float*)d_in[12];
  const float* W3   = (const float*)d_in[13];
  const float* b3   = (const float*)d_in[14];
  const float* ln2g = (const float*)d_in[15];
  const float* ln2b = (const float*)d_in[16];
  const float* Wd   = (const float*)d_in[17];
  const float* bd   = (const float*)d_in[18];

  // ---- workspace carve-up (f32 region then fp16 region; 16B aligned) ------
  float* ws = (float*)d_ws;
  float* kv     = ws;                         // 512*4096 f32
  float* att    = kv + ROWS * KVN;            // 262,144
  float* h3     = att + ROWS * HD;            // 262,144 (zeroed in prep)
  float* logits = h3 + ROWS * HD;             // 65,536
  float* kvb    = logits + ROWS * R;          // 4,608 bias (kv | shift)
  _Float16* hp = (_Float16*)(kvb + 4608);
  _Float16* flow_h = hp;            hp += 262144;
  _Float16* flow_l = hp;            hp += 262144;
  _Float16* BKV_h  = hp;            hp += 4608 * 512;  // Wk | Wv | Wsh, [n][k]
  _Float16* BKV_l  = hp;            hp += 4608 * 512;
  _Float16* W1_h   = hp;            hp += 2097152;
  _Float16* W1_l   = hp;            hp += 2097152;
  _Float16* W2_h   = hp;            hp += 4194304;
  _Float16* W2_l   = hp;            hp += 4194304;
  _Float16* W3_h   = hp;            hp += 2097152;
  _Float16* W3_l   = hp;            hp += 2097152;
  _Float16* Wd_h   = hp;            hp += 65536;
  _Float16* Wd_l   = hp;            hp += 65536;
  _Float16* att_h  = hp;            hp += 262144;
  _Float16* att_l  = hp;            hp += 262144;
  _Float16* h1_h   = hp;            hp += 524288;
  _Float16* h1_l   = hp;            hp += 524288;
  _Float16* h2_h   = hp;            hp += 524288;
  _Float16* h2_l   = hp;            hp += 524288;

  const int NSPLIT_NONE = 1 << 30;

  // ---- prep (flow split + h3 zero + bias vector), weight transpose+split --
  prep_kernel<<<512, 256, 0, stream>>>(flow, bk, bv, bsh, flow_h, flow_l, h3,
                                       kvb);
  WArgs wa;
  wa.s[0] = Wsh; wa.h[0] = BKV_h + 4096 * 512; wa.l[0] = BKV_l + 4096 * 512;
  wa.s[1] = Wk;  wa.h[1] = BKV_h;              wa.l[1] = BKV_l;
  wa.s[2] = Wv;  wa.h[2] = BKV_h + 2048 * 512; wa.l[2] = BKV_l + 2048 * 512;
  wa.s[3] = W1;  wa.h[3] = W1_h;  wa.l[3] = W1_l;
  wa.s[4] = W2;  wa.h[4] = W2_h;  wa.l[4] = W2_l;
  wa.s[5] = W3;  wa.h[5] = W3_h;  wa.l[5] = W3_l;
  wa.s[6] = Wd;  wa.h[6] = Wd_h;  wa.l[6] = Wd_l;
  wsplit_all<<<2640, 256, 0, stream>>>(wa);

  // ---- fused keys|vals|shift GEMM: [512 x 4608 x 512] ----
  mfma_gemm<<<dim3(8, 72, 1), 256, 0, stream>>>(
      flow_h, flow_l, BKV_h, BKV_l, kvb, kv, KVN, att, HD, KVN, nullptr,
      nullptr, 512, 0, 1);

  // ---- transformer layers ----
  for (int l = 0; l < L; l++) {
    attn_kernel<<<ROWS, 256, 0, stream>>>(att, att_h, att_l, kv, ln1g + l * HD,
                                          ln1b + l * HD, l);
    mfma_gemm<<<dim3(8, 16, 1), 256, 0, stream>>>(
        att_h, att_l, W1_h + (size_t)l * 524288, W1_l + (size_t)l * 524288,
        b1 + l * M, nullptr, M, nullptr, 0, NSPLIT_NONE, h1_h, h1_l, 512, 1,
        1);
    mfma_gemm<<<dim3(8, 16, 1), 256, 0, stream>>>(
        h1_h, h1_l, W2_h + (size_t)l * 1048576, W2_l + (size_t)l * 1048576,
        b2 + l * M, nullptr, M, nullptr, 0, NSPLIT_NONE, h2_h, h2_l, 1024, 1,
        1);
    mfma_gemm<<<dim3(8, 8, 2), 256, 0, stream>>>(
        h2_h, h2_l, W3_h + (size_t)l * 524288, W3_l + (size_t)l * 524288,
        b3 + l * HD, h3, HD, nullptr, 0, NSPLIT_NONE, nullptr, nullptr, 1024,
        0, 2);
    ln_res_kernel<<<ROWS, 256, 0, stream>>>(att, att_h, att_l, h3,
                                            ln2g + l * HD, ln2b + l * HD);
  }
  // ---- distribution head + sampling ----
  mfma_gemm<<<dim3(8, 2, 1), 256, 0, stream>>>(
      att_h, att_l, Wd_h, Wd_l, bd, logits, R, nullptr, 0, NSPLIT_NONE,
      nullptr, nullptr, 512, 0, 1);
  sample_kernel<<<SROWS / 4, 256, 0, stream>>>(logits, (float*)d_out);
}

// Round 7
// 435.821 us; speedup vs baseline: 4.5643x; 1.2114x over previous
//
#include <hip/hip_runtime.h>
#include <hip/hip_bf16.h>
#include <math.h>

// ---------------- problem dims (fixed by setup_inputs) ----------------
constexpr int B  = 8,  V = 64, E = 512, NS = 32;
constexpr int L  = 4,  H = 8,  D = 64,  M  = 1024, R = 128;
constexpr int HD = H * D;            // 512
constexpr int ROWS  = B * V;         // 512 distinct transformer rows
constexpr int SROWS = ROWS * NS;     // 16384 sample rows
constexpr int KVN = 4096;            // kv output columns (keys 2048 | vals 2048)

typedef _Float16 half8 __attribute__((ext_vector_type(8)));
typedef float floatx4 __attribute__((ext_vector_type(4)));

// ---------------- threefry2x32-20 (JAX-compatible, partitionable) ----------
struct TF2 { unsigned a, b; };
__host__ __device__ constexpr unsigned rotl32(unsigned x, int d) {
  return (x << d) | (x >> (32 - d));
}
__host__ __device__ constexpr TF2 threefry(unsigned k0, unsigned k1,
                                           unsigned x0, unsigned x1) {
  unsigned ks2 = k0 ^ k1 ^ 0x1BD11BDAu;
  x0 += k0; x1 += k1;
  const int ra[4] = {13, 15, 26, 6};
  const int rb[4] = {17, 29, 16, 24};
  for (int i = 0; i < 4; i++) { x0 += x1; x1 = rotl32(x1, ra[i]); x1 ^= x0; }
  x0 += k1;  x1 += ks2 + 1u;
  for (int i = 0; i < 4; i++) { x0 += x1; x1 = rotl32(x1, rb[i]); x1 ^= x0; }
  x0 += ks2; x1 += k0 + 2u;
  for (int i = 0; i < 4; i++) { x0 += x1; x1 = rotl32(x1, ra[i]); x1 ^= x0; }
  x0 += k0;  x1 += k1 + 3u;
  for (int i = 0; i < 4; i++) { x0 += x1; x1 = rotl32(x1, rb[i]); x1 ^= x0; }
  x0 += k1;  x1 += ks2 + 4u;
  for (int i = 0; i < 4; i++) { x0 += x1; x1 = rotl32(x1, ra[i]); x1 ^= x0; }
  x0 += ks2; x1 += k0 + 5u;
  return {x0, x1};
}
__device__ __forceinline__ unsigned tf_bits32(unsigned k0, unsigned k1,
                                              unsigned j) {
  TF2 r = threefry(k0, k1, 0u, j);
  return r.a ^ r.b;
}

__device__ __forceinline__ double waveReduceAdd64(double v) {
#pragma unroll
  for (int m = 32; m; m >>= 1) v += __shfl_xor(v, m, 64);
  return v;
}

__device__ __forceinline__ void split16(float v, _Float16& h, _Float16& l) {
  h = (_Float16)v;
  l = (_Float16)((v - (float)h) * 2048.0f);
}

// ---------------- prep: flow split + h3/logits zero + kv bias vector -------
__global__ __launch_bounds__(256) void prep_kernel(
    const float* __restrict__ flow, const float* __restrict__ bk,
    const float* __restrict__ bv, const float* __restrict__ bsh,
    _Float16* __restrict__ fh, _Float16* __restrict__ fl,
    float* __restrict__ h3, float* __restrict__ logits,
    float* __restrict__ kvb) {
  const int blk = blockIdx.x, t = threadIdx.x;
  if (blk < 256) {
    const int base = (blk * 256 + t) * 4;
    float4 v = *(const float4*)&flow[base];
    float a[4] = {v.x, v.y, v.z, v.w};
#pragma unroll
    for (int j = 0; j < 4; j++) {
      _Float16 h, l;
      split16(a[j], h, l);
      fh[base + j] = h;
      fl[base + j] = l;
    }
  } else if (blk < 512) {
    const int idx = (blk - 256) * 256 + t;
    float4 z = {0.f, 0.f, 0.f, 0.f};
    *(float4*)&h3[idx * 4] = z;
    if (idx < KVN + HD) {
      float bb = (idx < 2048) ? bk[idx]
               : (idx < 4096) ? bv[idx - 2048]
                              : bsh[idx - 4096];
      kvb[idx] = bb;
    }
  } else {
    const int idx = (blk - 512) * 256 + t;
    float4 z = {0.f, 0.f, 0.f, 0.f};
    *(float4*)&logits[idx * 4] = z;
  }
}

// ---------------- all-weights transpose + split in ONE launch --------------
struct WArgs {
  const float* s[7];
  _Float16* h[7];
  _Float16* l[7];
};
// 0 Wsh(512,512) 1 Wk(512,64)x32 2 Wv(512,64)x32 3 W1(512,1024)x4
// 4 W2(1024,1024)x4 5 W3(1024,512)x4 6 Wd(512,128)
__global__ __launch_bounds__(256) void wsplit_all(WArgs a) {
  const int WS_OFF[8] = {0, 64, 320, 576, 1088, 2112, 2624, 2640};
  const int WS_K[7] = {512, 512, 512, 512, 1024, 1024, 512};
  const int WS_N[7] = {512, 64, 64, 1024, 1024, 512, 128};
  __shared__ float tile[64][65];
  int bid = blockIdx.x;
  int mi = 0;
  while (bid >= WS_OFF[mi + 1]) mi++;
  int tt = bid - WS_OFF[mi];
  const int K = WS_K[mi], N = WS_N[mi];
  const int ktiles = K >> 6;
  const int per = ktiles * (N >> 6);
  const int z = tt / per;
  const int rem = tt - z * per;
  const int k0 = (rem % ktiles) * 64, n0 = (rem / ktiles) * 64;
  const size_t moff = (size_t)z * K * N;
  const float* src = a.s[mi] + moff;
  _Float16* dh = a.h[mi] + moff;
  _Float16* dl = a.l[mi] + moff;
  const int t = threadIdx.x;
#pragma unroll
  for (int i = 0; i < 16; i++) {
    int idx = i * 256 + t, r = idx >> 6, c = idx & 63;
    tile[r][c] = src[(size_t)(k0 + r) * N + n0 + c];
  }
  __syncthreads();
#pragma unroll
  for (int i = 0; i < 16; i++) {
    int idx = i * 256 + t, n = idx >> 6, k = idx & 63;
    float v = tile[k][n];
    _Float16 h, l;
    split16(v, h, l);
    dh[(size_t)(n0 + n) * K + k0 + k] = h;
    dl[(size_t)(n0 + n) * K + k0 + k] = l;
  }
}

// ---------------- 32x32 MFMA GEMM, BK=64, async LDS staging ----------------
// A_h/A_l: [M][K] fp16. B_h/B_l: [N][K] fp16. 16 KB/buffer, double-buffered.
// Fragment-order LDS: frag(X∈{Ah,Al,Bh,Bl}, r∈{0,1} row-half, s∈{0,1} ksub)
// at X*2048 + (r*2+s)*512 + lane*8 halfs — contiguous per-lane 16B, matches
// global_load_lds dest (wave-uniform base + lane*16) and bank-sweeps cleanly.
// Staging: wave w stages array w (4 gll/step). Compute: wave w owns 16x16
// tile (wm=w>>1, wn=w&1): per step 8 ds_read_b128 + 6 MFMA (2 ksubs x 3).
// kz==1: epilogue bias(+relu), route n<nsplit -> C0 else C1; opt h/l split.
// kz>1 : f32 atomicAdd into pre-zeroed C0 (deterministic for kz=2).
__global__ __launch_bounds__(256) void mfma_gemm(
    const _Float16* __restrict__ Ah, const _Float16* __restrict__ Al,
    const _Float16* __restrict__ Bh, const _Float16* __restrict__ Bl,
    const float* __restrict__ bias, float* __restrict__ C0, int ldc0,
    float* __restrict__ C1, int ldc1, int nsplit,
    _Float16* __restrict__ Oh, _Float16* __restrict__ Ol, int K, int relu,
    int kz) {
  __shared__ __align__(16) _Float16 lds[2 * 8192];
  const int t = threadIdx.x;
  const int lane = t & 63, wave = t >> 6;
  const int quad = lane >> 4, l15 = lane & 15;
  const int m0 = blockIdx.x * 32, n0 = blockIdx.y * 32;
  const int kchunk = K / kz, kbase = blockIdx.z * kchunk;
  const int KT = kchunk >> 6;  // BK = 64
  const _Float16* srcs[4] = {Ah + (size_t)m0 * K, Al + (size_t)m0 * K,
                             Bh + (size_t)n0 * K, Bl + (size_t)n0 * K};
  const _Float16* gsrc = srcs[wave];
  auto stage = [&](int buf, int kt) {
    _Float16* base = &lds[buf * 8192 + wave * 2048];
    const int kcol = kbase + kt * 64 + quad * 8;
#pragma unroll
    for (int r = 0; r < 2; r++)
#pragma unroll
      for (int s = 0; s < 2; s++)
        __builtin_amdgcn_global_load_lds(
            gsrc + (size_t)(r * 16 + l15) * K + kcol + s * 32,
            base + (r * 2 + s) * 512, 16, 0, 0);
  };
  const int wm = wave >> 1, wn = wave & 1;
  floatx4 hh = {0.f, 0.f, 0.f, 0.f};
  floatx4 mid = {0.f, 0.f, 0.f, 0.f};
  stage(0, 0);
  __syncthreads();
  for (int kt = 0; kt < KT; kt++) {
    if (kt + 1 < KT) stage((kt + 1) & 1, kt + 1);
    const int b = (kt & 1) * 8192;
#pragma unroll
    for (int s = 0; s < 2; s++) {
      const int afr = (wm * 2 + s) * 512 + lane * 8;
      const int bfr = (wn * 2 + s) * 512 + lane * 8;
      half8 a_h = *(const half8*)&lds[b + afr];
      half8 a_l = *(const half8*)&lds[b + 2048 + afr];
      half8 b_h = *(const half8*)&lds[b + 4096 + bfr];
      half8 b_l = *(const half8*)&lds[b + 6144 + bfr];
      hh = __builtin_amdgcn_mfma_f32_16x16x32_f16(a_h, b_h, hh, 0, 0, 0);
      mid = __builtin_amdgcn_mfma_f32_16x16x32_f16(a_h, b_l, mid, 0, 0, 0);
      mid = __builtin_amdgcn_mfma_f32_16x16x32_f16(a_l, b_h, mid, 0, 0, 0);
    }
    __syncthreads();
  }
#pragma unroll
  for (int r = 0; r < 4; r++) {
    float v = hh[r] + mid[r] * (1.0f / 2048.0f);
    const int m = m0 + wm * 16 + quad * 4 + r;
    const int n = n0 + wn * 16 + l15;
    if (kz == 1) {
      v += bias[n];
      if (relu) v = fmaxf(v, 0.0f);
      if (n < nsplit) {
        if (C0) C0[(size_t)m * ldc0 + n] = v;
        if (Oh) {
          _Float16 h, l;
          split16(v, h, l);
          Oh[(size_t)m * ldc0 + n] = h;
          Ol[(size_t)m * ldc0 + n] = l;
        }
      } else {
        C1[(size_t)m * ldc1 + (n - nsplit)] = v;
      }
    } else {
      if (blockIdx.z == 0) v += bias[n];
      atomicAdd(&C0[(size_t)m * ldc0 + n], v);
    }
  }
}

// ---------------- fused attention + residual + LN1 (one block per row) -----
// kv layout: kv[m=b*64+var][n], keys at n=(l*8+h)*64+d, vals at n+2048.
__global__ __launch_bounds__(256) void attn_kernel(
    float* __restrict__ att, _Float16* __restrict__ att_h,
    _Float16* __restrict__ att_l, const float* __restrict__ kv,
    const float* __restrict__ g, const float* __restrict__ bb, int l) {
  __shared__ float q[HD];
  __shared__ float sp[HD];
  __shared__ double rb[8];
  const int t = threadIdx.x;
  const int row = blockIdx.x;
  const int b_ = row >> 6;
  q[t]       = att[row * HD + t];
  q[t + 256] = att[row * HD + 256 + t];
  __syncthreads();
#pragma unroll
  for (int rep = 0; rep < 2; rep++) {
    int idx = t + rep * 256;
    int h = idx >> 6, w = idx & 63;
    const float* kp = kv + (size_t)(b_ * 64 + w) * KVN + (l * 8 + h) * 64;
    const float* qp = q + h * D;
    double s = 0.0;
#pragma unroll 8
    for (int d = 0; d < 64; d++) s += (double)qp[d] * (double)kp[d];
    sp[idx] = (float)s * 0.125f;
  }
  __syncthreads();
  {
    int h = t >> 5, w0 = t & 31;
    float s0 = sp[h * 64 + w0], s1 = sp[h * 64 + w0 + 32];
    float mx = fmaxf(s0, s1);
#pragma unroll
    for (int m = 16; m; m >>= 1) mx = fmaxf(mx, __shfl_xor(mx, m, 32));
    float e0 = expf(s0 - mx), e1 = expf(s1 - mx);
    double sm = (double)e0 + (double)e1;
#pragma unroll
    for (int m = 16; m; m >>= 1) sm += __shfl_xor(sm, m, 32);
    sp[h * 64 + w0]      = (float)((double)e0 / sm);
    sp[h * 64 + w0 + 32] = (float)((double)e1 / sm);
  }
  __syncthreads();
  float x[2];
#pragma unroll
  for (int rep = 0; rep < 2; rep++) {
    int idx = t + rep * 256;
    int h = idx >> 6, d = idx & 63;
    const float* vp = kv + (size_t)(b_ * 64) * KVN + 2048 + (l * 8 + h) * 64 + d;
    const float* pp = sp + h * 64;
    double a = 0.0;
#pragma unroll 8
    for (int w = 0; w < 64; w++) a += (double)pp[w] * (double)vp[(size_t)w * KVN];
    x[rep] = q[idx] + (float)a;
  }
  double s1 = (double)x[0] + (double)x[1];
  double s2 = (double)x[0] * (double)x[0] + (double)x[1] * (double)x[1];
  s1 = waveReduceAdd64(s1);
  s2 = waveReduceAdd64(s2);
  const int wid = t >> 6, lane = t & 63;
  if (lane == 0) { rb[wid] = s1; rb[4 + wid] = s2; }
  __syncthreads();
  double S1 = rb[0] + rb[1] + rb[2] + rb[3];
  double S2 = rb[4] + rb[5] + rb[6] + rb[7];
  double mean = S1 / (double)HD;
  double var  = S2 / (double)HD - mean * mean;
  double inv  = 1.0 / sqrt(var + (double)1e-5f);
  float y0 =
      (float)(((double)x[0] - mean) * inv * (double)g[t] + (double)bb[t]);
  float y1 = (float)(((double)x[1] - mean) * inv * (double)g[t + 256] +
                     (double)bb[t + 256]);
  att[row * HD + t] = y0;
  att[row * HD + 256 + t] = y1;
  _Float16 h0, l0, h1v, l1v;
  split16(y0, h0, l0);
  split16(y1, h1v, l1v);
  att_h[row * HD + t] = h0;
  att_l[row * HD + t] = l0;
  att_h[row * HD + 256 + t] = h1v;
  att_l[row * HD + 256 + t] = l1v;
}

// ---------------- residual + LN2 (consumes f32 h3, re-zeros it) ------------
__global__ __launch_bounds__(256) void ln_res_kernel(
    float* __restrict__ att, _Float16* __restrict__ att_h,
    _Float16* __restrict__ att_l, float* __restrict__ h3,
    const float* __restrict__ g, const float* __restrict__ bb) {
  __shared__ double rb[8];
  const int t = threadIdx.x;
  const int row = blockIdx.x;
  float x0 = att[row * HD + t] + h3[row * HD + t];
  float x1 = att[row * HD + 256 + t] + h3[row * HD + 256 + t];
  h3[row * HD + t] = 0.0f;
  h3[row * HD + 256 + t] = 0.0f;
  double s1 = (double)x0 + (double)x1;
  double s2 = (double)x0 * (double)x0 + (double)x1 * (double)x1;
  s1 = waveReduceAdd64(s1);
  s2 = waveReduceAdd64(s2);
  const int wid = t >> 6, lane = t & 63;
  if (lane == 0) { rb[wid] = s1; rb[4 + wid] = s2; }
  __syncthreads();
  double S1 = rb[0] + rb[1] + rb[2] + rb[3];
  double S2 = rb[4] + rb[5] + rb[6] + rb[7];
  double mean = S1 / (double)HD;
  double var  = S2 / (double)HD - mean * mean;
  double inv  = 1.0 / sqrt(var + (double)1e-5f);
  float y0 = (float)(((double)x0 - mean) * inv * (double)g[t] + (double)bb[t]);
  float y1 = (float)(((double)x1 - mean) * inv * (double)g[t + 256] +
                     (double)bb[t + 256]);
  att[row * HD + t] = y0;
  att[row * HD + 256 + t] = y1;
  _Float16 h0, l0, h1v, l1v;
  split16(y0, h0, l0);
  split16(y1, h1v, l1v);
  att_h[row * HD + t] = h0;
  att_l[row * HD + t] = l0;
  att_h[row * HD + 256 + t] = h1v;
  att_l[row * HD + 256 + t] = l1v;
}

// ---------------- gumbel-argmax sampling (bit-exact vs JAX; verified) ------
__global__ __launch_bounds__(256) void sample_kernel(
    const float* __restrict__ logits, float* __restrict__ out) {
  constexpr TF2 KC = threefry(0u, 1u, 0u, 0u);  // fold_in(key(1), 0)
  constexpr TF2 KU = threefry(0u, 1u, 0u, 1u);  // fold_in(key(1), 1)
  const int lane = threadIdx.x & 63;
  const int wid = threadIdx.x >> 6;
  const int row = blockIdx.x * 4 + wid;
  const float* lrow = logits + (row >> 5) * R;
  float bvv = -1e30f;
  int bi = 0;
#pragma unroll
  for (int rep = 0; rep < 2; rep++) {
    int r = lane + rep * 64;
    unsigned j = (unsigned)row * (unsigned)R + (unsigned)r;
    unsigned bits = tf_bits32(KC.a, KC.b, j);
    float f = __uint_as_float((bits >> 9) | 0x3f800000u) - 1.0f;
    float u = fmaxf(f, 1.17549435e-38f);
    float gv = -logf(-logf(u));
    float v = lrow[r] + gv;
    if (v > bvv) { bvv = v; bi = r; }
  }
#pragma unroll
  for (int m = 32; m; m >>= 1) {
    float ov = __shfl_xor(bvv, m, 64);
    int oi = __shfl_xor(bi, m, 64);
    if (ov > bvv || (ov == bvv && oi < bi)) { bvv = ov; bi = oi; }
  }
  if (lane == 0) {
    unsigned ub = tf_bits32(KU.a, KU.b, (unsigned)row);
    float u = __uint_as_float((ub >> 9) | 0x3f800000u) - 1.0f;
    out[row] = ((float)bi + u) * (1.0f / 128.0f);
  }
}

// ---------------- launcher ----------------
extern "C" void kernel_launch(void* const* d_in, const int* in_sizes, int n_in,
                              void* d_out, int out_size, void* d_ws,
                              size_t ws_size, hipStream_t stream) {
  (void)in_sizes; (void)n_in; (void)out_size; (void)ws_size;
  const float* flow = (const float*)d_in[0];
  const float* Wsh  = (const float*)d_in[1];
  const float* bsh  = (const float*)d_in[2];
  const float* Wk   = (const float*)d_in[3];
  const float* bk   = (const float*)d_in[4];
  const float* Wv   = (const float*)d_in[5];
  const float* bv   = (const float*)d_in[6];
  const float* ln1g = (const float*)d_in[7];
  const float* ln1b = (const float*)d_in[8];
  const float* W1   = (const float*)d_in[9];
  const float* b1   = (const float*)d_in[10];
  const float* W2   = (const float*)d_in[11];
  const float* b2   = (const float*)d_in[12];
  const float* W3   = (const float*)d_in[13];
  const float* b3   = (const float*)d_in[14];
  const float* ln2g = (const float*)d_in[15];
  const float* ln2b = (const float*)d_in[16];
  const float* Wd   = (const float*)d_in[17];
  const float* bd   = (const float*)d_in[18];

  // ---- workspace carve-up (f32 region then fp16 region; 16B aligned) ------
  float* ws = (float*)d_ws;
  float* kv     = ws;                         // 512*4096 f32
  float* att    = kv + ROWS * KVN;            // 262,144
  float* h3     = att + ROWS * HD;            // 262,144 (zeroed in prep)
  float* logits = h3 + ROWS * HD;             // 65,536  (zeroed in prep)
  float* kvb    = logits + ROWS * R;          // 4,608 bias (kv | shift)
  _Float16* hp = (_Float16*)(kvb + 4608);
  _Float16* flow_h = hp;            hp += 262144;
  _Float16* flow_l = hp;            hp += 262144;
  _Float16* BKV_h  = hp;            hp += 4608 * 512;  // Wk | Wv | Wsh, [n][k]
  _Float16* BKV_l  = hp;            hp += 4608 * 512;
  _Float16* W1_h   = hp;            hp += 2097152;
  _Float16* W1_l   = hp;            hp += 2097152;
  _Float16* W2_h   = hp;            hp += 4194304;
  _Float16* W2_l   = hp;            hp += 4194304;
  _Float16* W3_h   = hp;            hp += 2097152;
  _Float16* W3_l   = hp;            hp += 2097152;
  _Float16* Wd_h   = hp;            hp += 65536;
  _Float16* Wd_l   = hp;            hp += 65536;
  _Float16* att_h  = hp;            hp += 262144;
  _Float16* att_l  = hp;            hp += 262144;
  _Float16* h1_h   = hp;            hp += 524288;
  _Float16* h1_l   = hp;            hp += 524288;
  _Float16* h2_h   = hp;            hp += 524288;
  _Float16* h2_l   = hp;            hp += 524288;

  const int NSPLIT_NONE = 1 << 30;

  // ---- prep (flow split + zeros + bias vector), weight transpose+split ----
  prep_kernel<<<576, 256, 0, stream>>>(flow, bk, bv, bsh, flow_h, flow_l, h3,
                                       logits, kvb);
  WArgs wa;
  wa.s[0] = Wsh; wa.h[0] = BKV_h + 4096 * 512; wa.l[0] = BKV_l + 4096 * 512;
  wa.s[1] = Wk;  wa.h[1] = BKV_h;              wa.l[1] = BKV_l;
  wa.s[2] = Wv;  wa.h[2] = BKV_h + 2048 * 512; wa.l[2] = BKV_l + 2048 * 512;
  wa.s[3] = W1;  wa.h[3] = W1_h;  wa.l[3] = W1_l;
  wa.s[4] = W2;  wa.h[4] = W2_h;  wa.l[4] = W2_l;
  wa.s[5] = W3;  wa.h[5] = W3_h;  wa.l[5] = W3_l;
  wa.s[6] = Wd;  wa.h[6] = Wd_h;  wa.l[6] = Wd_l;
  wsplit_all<<<2640, 256, 0, stream>>>(wa);

  // ---- fused keys|vals|shift GEMM: [512 x 4608 x 512] ----
  mfma_gemm<<<dim3(16, 144, 1), 256, 0, stream>>>(
      flow_h, flow_l, BKV_h, BKV_l, kvb, kv, KVN, att, HD, KVN, nullptr,
      nullptr, 512, 0, 1);

  // ---- transformer layers ----
  for (int l = 0; l < L; l++) {
    attn_kernel<<<ROWS, 256, 0, stream>>>(att, att_h, att_l, kv, ln1g + l * HD,
                                          ln1b + l * HD, l);
    mfma_gemm<<<dim3(16, 32, 1), 256, 0, stream>>>(
        att_h, att_l, W1_h + (size_t)l * 524288, W1_l + (size_t)l * 524288,
        b1 + l * M, nullptr, M, nullptr, 0, NSPLIT_NONE, h1_h, h1_l, 512, 1,
        1);
    mfma_gemm<<<dim3(16, 32, 1), 256, 0, stream>>>(
        h1_h, h1_l, W2_h + (size_t)l * 1048576, W2_l + (size_t)l * 1048576,
        b2 + l * M, nullptr, M, nullptr, 0, NSPLIT_NONE, h2_h, h2_l, 1024, 1,
        1);
    mfma_gemm<<<dim3(16, 16, 2), 256, 0, stream>>>(
        h2_h, h2_l, W3_h + (size_t)l * 524288, W3_l + (size_t)l * 524288,
        b3 + l * HD, h3, HD, nullptr, 0, NSPLIT_NONE, nullptr, nullptr, 1024,
        0, 2);
    ln_res_kernel<<<ROWS, 256, 0, stream>>>(att, att_h, att_l, h3,
                                            ln2g + l * HD, ln2b + l * HD);
  }
  // ---- distribution head + sampling ----
  mfma_gemm<<<dim3(16, 4, 2), 256, 0, stream>>>(
      att_h, att_l, Wd_h, Wd_l, bd, logits, R, nullptr, 0, NSPLIT_NONE,
      nullptr, nullptr, 512, 0, 2);
  sample_kernel<<<SROWS / 4, 256, 0, stream>>>(logits, (float*)d_out);
}